// Round 16
// baseline (10407.691 us; speedup 1.0000x reference)
//
#include <hip/hip_runtime.h>
#include <math.h>

#define FH 384
#define KF 193
#define SPW 147456

typedef __attribute__((ext_vector_type(8))) short short8;
typedef __attribute__((ext_vector_type(4))) float f32x4;
typedef unsigned int u32;
typedef unsigned short u16;

static __device__ __forceinline__ float softt(float v, float b) {
    return copysignf(fmaxf(fabsf(v) - b, 0.f), v);
}
static __device__ __forceinline__ u16 bf16_rn(float v) {
    u32 u = __float_as_uint(v);
    u32 r = (u + 0x7FFFu + ((u >> 16) & 1u)) >> 16;
    return (u16)r;
}
static __device__ __forceinline__ float bf16_to_f(u16 h) {
    return __uint_as_float(((u32)h) << 16);
}
// complex spectra stored as uint2: .x = H-word (bf16 re | bf16 im<<16), .y = L-word
static __device__ __forceinline__ float2 ldc(const uint2* __restrict__ S, size_t i) {
    uint2 u = S[i];
    float2 r;
    r.x = __uint_as_float((u.x & 0xffffu) << 16) + __uint_as_float((u.y & 0xffffu) << 16);
    r.y = __uint_as_float(u.x & 0xffff0000u) + __uint_as_float(u.y & 0xffff0000u);
    return r;
}
static __device__ __forceinline__ float2 ldcu(uint2 u) {
    float2 r;
    r.x = __uint_as_float((u.x & 0xffffu) << 16) + __uint_as_float((u.y & 0xffffu) << 16);
    r.y = __uint_as_float(u.x & 0xffff0000u) + __uint_as_float(u.y & 0xffff0000u);
    return r;
}
static __device__ __forceinline__ uint2 packc(float re, float im) {
    u16 hr = bf16_rn(re), hi = bf16_rn(im);
    u16 lr = bf16_rn(re - bf16_to_f(hr)), li = bf16_rn(im - bf16_to_f(hi));
    uint2 o; o.x = (u32)hr | ((u32)hi << 16); o.y = (u32)lr | ((u32)li << 16);
    return o;
}
static __device__ __forceinline__ float2 cmul(float2 a, float2 b) {
    float2 r; r.x = a.x*b.x - a.y*b.y; r.y = a.x*b.y + a.y*b.x; return r;
}

// 8-point DIT butterfly over twiddled 48-DFT partials (shared by fwd/inv col passes)
static __device__ __forceinline__ void bfly8(const float2 cc[8], int h0, float sgn,
                                             const float2* __restrict__ twT, float2 X[8])
{
    const float rt = 0.70710678118654752f;
    float2 d[8];
    d[0] = cc[0];
#pragma unroll
    for (int p = 1; p < 8; ++p) {
        float2 w = twT[p*h0];
        w.y *= sgn;
        d[p] = cmul(cc[p], w);
    }
    float2 e0, e1, e2, e3, o0, o1, o2, o3;
    e0.x = d[0].x + d[4].x; e0.y = d[0].y + d[4].y;
    e1.x = d[1].x + d[5].x; e1.y = d[1].y + d[5].y;
    e2.x = d[2].x + d[6].x; e2.y = d[2].y + d[6].y;
    e3.x = d[3].x + d[7].x; e3.y = d[3].y + d[7].y;
    o0.x = d[0].x - d[4].x; o0.y = d[0].y - d[4].y;
    o1.x = d[1].x - d[5].x; o1.y = d[1].y - d[5].y;
    o2.x = d[2].x - d[6].x; o2.y = d[2].y - d[6].y;
    o3.x = d[3].x - d[7].x; o3.y = d[3].y - d[7].y;
    float2 s02, m02, s13, m13, i13;
    s02.x = e0.x + e2.x; s02.y = e0.y + e2.y;
    m02.x = e0.x - e2.x; m02.y = e0.y - e2.y;
    s13.x = e1.x + e3.x; s13.y = e1.y + e3.y;
    m13.x = e1.x - e3.x; m13.y = e1.y - e3.y;
    i13.x = -sgn*m13.y;  i13.y = sgn*m13.x;
    X[0].x = s02.x + s13.x; X[0].y = s02.y + s13.y;
    X[4].x = s02.x - s13.x; X[4].y = s02.y - s13.y;
    X[2].x = m02.x + i13.x; X[2].y = m02.y + i13.y;
    X[6].x = m02.x - i13.x; X[6].y = m02.y - i13.y;
    float2 g0 = o0, g1, g2, g3;
    g1.x = rt*(o1.x - sgn*o1.y);  g1.y = rt*(sgn*o1.x + o1.y);       // *w8
    g2.x = -sgn*o2.y;             g2.y = sgn*o2.x;                   // *w4
    g3.x = rt*(-(o3.x + sgn*o3.y)); g3.y = rt*(sgn*o3.x - o3.y);     // *w8^3
    float2 sp, mp, sq, mq, iq;
    sp.x = g0.x + g2.x; sp.y = g0.y + g2.y;
    mp.x = g0.x - g2.x; mp.y = g0.y - g2.y;
    sq.x = g1.x + g3.x; sq.y = g1.y + g3.y;
    mq.x = g1.x - g3.x; mq.y = g1.y - g3.y;
    iq.x = -sgn*mq.y;   iq.y = sgn*mq.x;
    X[1].x = sp.x + sq.x; X[1].y = sp.y + sq.y;
    X[5].x = sp.x - sq.x; X[5].y = sp.y - sq.y;
    X[3].x = mp.x + iq.x; X[3].y = mp.y + iq.y;
    X[7].x = mp.x - iq.x; X[7].y = mp.y - iq.y;
}

// ---------------- tables ----------------
__global__ void init_ef_k(float2* Ef) {
    int idx = blockIdx.x * 256 + threadIdx.x;
    if (idx >= FH * FH) return;
    int h = idx / FH, j = idx % FH;
    int m = (h * j) % FH;
    float th = (float)(6.283185307179586 / FH) * (float)m;
    float2 v; v.x = cosf(th); v.y = -sinf(th);
    Ef[idx] = v;
}

// twiddle table: twT[h] = (cos(2*pi*h/384), sin(2*pi*h/384)), h in [0,384)
__global__ void init_tw(float2* twT) {
    int i = blockIdx.x * 256 + threadIdx.x;
    if (i < 384) {
        float th = (float)(6.283185307179586 / 384.0) * (float)i;
        float2 v; v.x = cosf(th); v.y = sinf(th);
        twT[i] = v;
    }
}

// E48: stacked-real 48-point DFT matrix (96x96), radix-8 col pass.
// Inverse bakes the FULL 1/384 scale.
__global__ void init_e48(u16* __restrict__ H, u16* __restrict__ L, int inv)
{
    int idx = blockIdx.x * 256 + threadIdx.x;
    if (idx >= 96 * 96) return;
    int gm = idx / 96, kp = idx % 96;
    int m = gm >> 1, comp = gm & 1;
    int t = kp >> 1, ri = kp & 1;
    int mm = (m * t) % 48;
    float th = (float)(6.283185307179586 / 48.0) * (float)mm;
    float c = cosf(th), s = sinf(th);
    float er, ei;
    if (inv) { er = c * (1.f/384.f); ei = s * (1.f/384.f); }
    else     { er = c;               ei = -s; }
    float v;
    if (comp == 0) v = (ri == 0) ? er : -ei;
    else           v = (ri == 0) ? ei :  er;
    u16 h = bf16_rn(v);
    H[idx] = h;
    L[idx] = bf16_rn(v - bf16_to_f(h));
}

// Tt192: row-pass forward 192-pt DFT matrix, [n:208 stacked][m:192]
__global__ void init_t192(u16* __restrict__ H, u16* __restrict__ L)
{
    int idx = blockIdx.x * 256 + threadIdx.x;
    if (idx >= 208 * 192) return;
    int n = idx / 192, m = idx % 192;
    float v = 0.f;
    if (n < 194) {
        int j = n >> 1, ri = n & 1;
        int mm = (j * m) % 192;
        float th = (float)(6.283185307179586 / 192.0) * (float)mm;
        v = ri ? -sinf(th) : cosf(th);
    }
    u16 h = bf16_rn(v);
    H[idx] = h;
    L[idx] = bf16_rn(v - bf16_to_f(h));
}

// Ut192: row-pass inverse fold matrix, [m:192][kk:224], weights 1/384 | 2/384
__global__ void init_u192(u16* __restrict__ H, u16* __restrict__ L)
{
    int idx = blockIdx.x * 256 + threadIdx.x;
    if (idx >= 192 * 224) return;
    int m = idx / 224, kk = idx % 224;
    float v = 0.f;
    if (kk < 194) {
        int j = kk >> 1, ri = kk & 1;
        float cj = (j == 0 || j == 96) ? (1.f/384.f) : (2.f/384.f);
        int mm = (j * m) % 192;
        float th = (float)(6.283185307179586 / 192.0) * (float)mm;
        v = ri ? -cj*sinf(th) : cj*cosf(th);
    }
    u16 h = bf16_rn(v);
    H[idx] = h;
    L[idx] = bf16_rn(v - bf16_to_f(h));
}

// ---------------- w0 centering ----------------
__global__ void w0c_kernel(const float* __restrict__ w0, float* __restrict__ w0c) {
    int t = threadIdx.x;
    if (t < 48) {
        float m = 0.f;
        for (int d = 0; d < 9; ++d) m += w0[t*9+d];
        m *= (1.f/9.f);
        for (int d = 0; d < 9; ++d) w0c[t*9+d] = w0[t*9+d] - m;
    }
}

// ---------------- 3x3 conv: input fp32 (first) or split H/L (de-interleaved);
// output split H/L, parity-de-interleaved rows: [even x block | odd x block] ----------------
__global__ __launch_bounds__(256) void conv3x3_kernel(
    const float* __restrict__ inpF0, const u16* __restrict__ inH0, const u16* __restrict__ inL0,
    const float* __restrict__ w,
    u16* __restrict__ outH0, u16* __restrict__ outL0, int Cin, int flip,
    size_t inImgStride)
{
    size_t iofs = (size_t)blockIdx.z * inImgStride;
    const float* inF = inpF0 ? inpF0 + iofs : nullptr;
    const u16*   iH  = inH0 ? inH0 + iofs : nullptr;
    const u16*   iL  = inL0 ? inL0 + iofs : nullptr;
    u16* oH = outH0 + (size_t)blockIdx.z * 16*65536;
    u16* oL = outL0 + (size_t)blockIdx.z * 16*65536;
    __shared__ float tile[18][19];
    __shared__ float wl[16*16*9];
    int x0 = blockIdx.x * 16, y0 = blockIdx.y * 16;
    int t = threadIdx.x;
    int tx = t & 15, ty = t >> 4;
    int nw = 16 * Cin * 9;
    for (int i = t; i < nw; i += 256) {
        int d = i % 9;
        wl[i] = flip ? w[i + 8 - 2*d] : w[i];
    }
    float acc[16];
#pragma unroll
    for (int co = 0; co < 16; ++co) acc[co] = 0.f;
    for (int ci = 0; ci < Cin; ++ci) {
        __syncthreads();
        for (int i = t; i < 18*18; i += 256) {
            int yy = i / 18, xx = i % 18;
            int gy = y0 - 1 + yy, gx = x0 - 1 + xx;
            float v = 0.f;
            if (gy >= 0 && gy < 256 && gx >= 0 && gx < 256) {
                size_t ii;
                if (inF) ii = ((size_t)ci*256 + gy)*256 + gx;
                else     ii = ((size_t)ci*256 + gy)*256 + ((gx>>1) + (gx&1)*128);
                v = inF ? inF[ii] : (bf16_to_f(iH[ii]) + bf16_to_f(iL[ii]));
            }
            tile[yy][xx] = v;
        }
        __syncthreads();
        float v[9];
#pragma unroll
        for (int dy = 0; dy < 3; dy++)
#pragma unroll
            for (int dx = 0; dx < 3; dx++) v[dy*3+dx] = tile[ty+dy][tx+dx];
#pragma unroll
        for (int co = 0; co < 16; co++) {
            const float* wp = &wl[(co*Cin+ci)*9];
            acc[co] += v[0]*wp[0]+v[1]*wp[1]+v[2]*wp[2]
                     + v[3]*wp[3]+v[4]*wp[4]+v[5]*wp[5]
                     + v[6]*wp[6]+v[7]*wp[7]+v[8]*wp[8];
        }
    }
    int xo = x0 + tx;
    int xd = (xo >> 1) + (xo & 1)*128;
#pragma unroll
    for (int co = 0; co < 16; co++) {
        size_t o = ((size_t)co*256 + (y0+ty))*256 + xd;
        u16 h = bf16_rn(acc[co]);
        oH[o] = h;
        oL[o] = bf16_rn(acc[co] - bf16_to_f(h));
    }
}

// ---------------- z init: circshift(22,22) of padded split fy9 + soft threshold,
// writes split H/L de-interleaved (FH-wide rows: [192 even | 192 odd]) ------
__global__ void zinit_kernel(const u16* __restrict__ fy9H, const u16* __restrict__ fy9L,
                             const float* __restrict__ b0,
                             u16* __restrict__ oH, u16* __restrict__ oL, int total)
{
    int idx = blockIdx.x*256 + threadIdx.x;
    if (idx >= total) return;
    int x = idx % FH; int r = idx / FH; int y = r % FH; int plane = r / FH;
    int c = plane & 15;
    int Y = y + 22; if (Y >= FH) Y -= FH;
    int X = x + 22; if (X >= FH) X -= FH;
    int yy = Y - 44, xx = X - 44;
    float v = 0.f;
    if (yy >= 0 && yy < 256 && xx >= 0 && xx < 256) {
        size_t ii = ((size_t)plane*256 + yy)*256 + ((xx>>1) + (xx&1)*128);
        v = bf16_to_f(fy9H[ii]) + bf16_to_f(fy9L[ii]);
    }
    float s = softt(v, b0[c]);
    u16 h = bf16_rn(s);
    size_t d = (size_t)plane*SPW + (size_t)y*FH + ((x>>1) + (x&1)*192);
    oH[d] = h;
    oL[d] = bf16_rn(s - bf16_to_f(h));
}

// ---------------- shared epilogue for radix-2 row R2C ----------------
static __device__ __forceinline__ void r2c192_epilogue(
    f32x4 accA[2][4], f32x4 accB[2][4],
    int col0, int njN, int y0, int wave, int lm, int lq,
    const float2* __restrict__ twT,
    uint2* __restrict__ outp, int B, int plane)
{
#pragma unroll
    for (int mi = 0; mi < 2; ++mi) {
#pragma unroll
        for (int nj = 0; nj < 4; ++nj) {
            if (nj >= njN) continue;
            int n = col0 + nj*16 + lm;
            int j = n >> 1;
            float pA[4], pB[4];
#pragma unroll
            for (int rr = 0; rr < 4; ++rr) {
                pA[rr] = __shfl_xor(accA[mi][nj][rr], 1);
                pB[rr] = __shfl_xor(accB[mi][nj][rr], 1);
            }
            if (((lm & 1) == 0) && j <= 96) {
                float2 tw = twT[j];
                float wr = tw.x, wi = -tw.y;
                int ybase = y0 + wave*32 + mi*16 + lq*4;
#pragma unroll
                for (int rr = 0; rr < 4; ++rr) {
                    float ar = accA[mi][nj][rr], ai = pA[rr];
                    float br = accB[mi][nj][rr], bi = pB[rr];
                    float tr = wr*br - wi*bi;
                    float ti = wr*bi + wi*br;
                    size_t rowb = ((size_t)(ybase+rr)*B + plane)*KF;
                    outp[rowb + j] = packc(ar + tr, ai + ti);
                    if (j < 96) outp[rowb + 192 - j] = packc(ar - tr, -(ai - ti));
                }
            }
        }
    }
}

// ---------------- radix-2 MFMA row pass R2C (fp32 source, fused softt) ----------------
__global__ __launch_bounds__(256) void r2c192_f(
    const float* __restrict__ inp, int inH, int inW, int inStride, size_t planeStride,
    int offY, int offX,
    const float* __restrict__ thr,
    const u16* __restrict__ TH, const u16* __restrict__ TL,
    const float2* __restrict__ twT,
    uint2* __restrict__ outp, int B)
{
    __shared__ u16 AhS[2][8*64*8];
    __shared__ u16 AlS[2][8*64*8];
    int col0 = blockIdx.x * 64;
    int y0   = blockIdx.y * 128;
    int plane = blockIdx.z;
    int njN = (col0 >= 192) ? 1 : 4;
    int tid = threadIdx.x;
    int wave = tid >> 6, lane = tid & 63;
    int lm = lane & 15, lq = lane >> 4;
    f32x4 accA[2][4], accB[2][4];
#pragma unroll
    for (int mi = 0; mi < 2; ++mi)
#pragma unroll
        for (int nj = 0; nj < 4; ++nj) {
            accA[mi][nj] = (f32x4){0.f,0.f,0.f,0.f};
            accB[mi][nj] = (f32x4){0.f,0.f,0.f,0.f};
        }
    float bthr = thr ? thr[plane & 15] : 0.f;
    const float* inpP = inp + (size_t)plane*planeStride;
    int mhi = (offX + inW) >> 1;   // offX even
    for (int kt = 0; kt < mhi; kt += 32) {
#pragma unroll
        for (int s = 0; s < 4; ++s) {
            int slot = tid + s*256;
            int r = slot >> 3, kq = slot & 7;
            int yy = y0 + r - offY;
            int xx0 = 2*(kt + kq*4) - offX;
            float v[8];
#pragma unroll
            for (int d = 0; d < 8; ++d) {
                int xx = xx0 + d;
                float t = 0.f;
                if (yy >= 0 && yy < inH && xx >= 0 && xx < inW)
                    t = inpP[(size_t)yy*inStride + xx];
                if (thr) t = softt(t, bthr);
                v[d] = t;
            }
            u16 h[8], l[8];
#pragma unroll
            for (int d = 0; d < 8; ++d) {
                h[d] = bf16_rn(v[d]);
                l[d] = bf16_rn(v[d] - bf16_to_f(h[d]));
            }
            int base = ((r >> 4)*64 + (r & 15) + 16*(kq >> 1))*8 + (kq & 1)*4;
            uint2 w;
            w.x = (u32)h[0] | ((u32)h[2] << 16); w.y = (u32)h[4] | ((u32)h[6] << 16);
            *(uint2*)&AhS[0][base] = w;
            w.x = (u32)h[1] | ((u32)h[3] << 16); w.y = (u32)h[5] | ((u32)h[7] << 16);
            *(uint2*)&AhS[1][base] = w;
            w.x = (u32)l[0] | ((u32)l[2] << 16); w.y = (u32)l[4] | ((u32)l[6] << 16);
            *(uint2*)&AlS[0][base] = w;
            w.x = (u32)l[1] | ((u32)l[3] << 16); w.y = (u32)l[5] | ((u32)l[7] << 16);
            *(uint2*)&AlS[1][base] = w;
        }
        __syncthreads();
        short8 A0h[2], A0l[2], A1h[2], A1l[2];
#pragma unroll
        for (int mi = 0; mi < 2; ++mi) {
            int fo = ((wave*2 + mi)*64 + lane)*8;
            A0h[mi] = *(const short8*)&AhS[0][fo];
            A0l[mi] = *(const short8*)&AlS[0][fo];
            A1h[mi] = *(const short8*)&AhS[1][fo];
            A1l[mi] = *(const short8*)&AlS[1][fo];
        }
#pragma unroll
        for (int nj = 0; nj < 4; ++nj) {
            if (nj >= njN) continue;
            size_t toff = (size_t)(col0 + nj*16 + lm)*192 + kt + lq*8;
            short8 Bh = *(const short8*)(TH + toff);
            short8 Bl = *(const short8*)(TL + toff);
#pragma unroll
            for (int mi = 0; mi < 2; ++mi) {
                accA[mi][nj] = __builtin_amdgcn_mfma_f32_16x16x32_bf16(A0h[mi], Bh, accA[mi][nj], 0, 0, 0);
                accA[mi][nj] = __builtin_amdgcn_mfma_f32_16x16x32_bf16(A0h[mi], Bl, accA[mi][nj], 0, 0, 0);
                accA[mi][nj] = __builtin_amdgcn_mfma_f32_16x16x32_bf16(A0l[mi], Bh, accA[mi][nj], 0, 0, 0);
                accB[mi][nj] = __builtin_amdgcn_mfma_f32_16x16x32_bf16(A1h[mi], Bh, accB[mi][nj], 0, 0, 0);
                accB[mi][nj] = __builtin_amdgcn_mfma_f32_16x16x32_bf16(A1h[mi], Bl, accB[mi][nj], 0, 0, 0);
                accB[mi][nj] = __builtin_amdgcn_mfma_f32_16x16x32_bf16(A1l[mi], Bh, accB[mi][nj], 0, 0, 0);
            }
        }
        __syncthreads();
    }
    r2c192_epilogue(accA, accB, col0, njN, y0, wave, lm, lq, twT, outp, B, plane);
}

// ---------------- radix-2 MFMA row pass R2C (pre-split de-interleaved H/L source) --------
__global__ __launch_bounds__(256) void r2c192_s(
    const u16* __restrict__ Hs, const u16* __restrict__ Ls,
    int inH, int inW, int offY, int offX,
    const u16* __restrict__ TH, const u16* __restrict__ TL,
    const float2* __restrict__ twT,
    uint2* __restrict__ outp, int B)
{
    __shared__ u16 AhS[2][8*64*8];
    __shared__ u16 AlS[2][8*64*8];
    int col0 = blockIdx.x * 64;
    int y0   = blockIdx.y * 128;
    int plane = blockIdx.z;
    int njN = (col0 >= 192) ? 1 : 4;
    int tid = threadIdx.x;
    int wave = tid >> 6, lane = tid & 63;
    int lm = lane & 15, lq = lane >> 4;
    f32x4 accA[2][4], accB[2][4];
#pragma unroll
    for (int mi = 0; mi < 2; ++mi)
#pragma unroll
        for (int nj = 0; nj < 4; ++nj) {
            accA[mi][nj] = (f32x4){0.f,0.f,0.f,0.f};
            accB[mi][nj] = (f32x4){0.f,0.f,0.f,0.f};
        }
    const u16* hP = Hs + (size_t)plane*inH*inW;
    const u16* lP = Ls + (size_t)plane*inH*inW;
    int W2  = inW >> 1;
    int ox2 = offX >> 1;
    bool al16 = ((ox2 & 7) == 0);
    int mhi = (offX + inW) >> 1;   // offX even
    for (int kt = 0; kt < mhi; kt += 32) {
        // slots: 2 parities x 128 rows x 4 kq2 (8 m each) = 1024
#pragma unroll
        for (int s = 0; s < 4; ++s) {
            int slot = tid + s*256;
            int p    = slot >> 9;
            int inr  = slot & 511;
            int r = inr >> 2, kq2 = inr & 3;
            int yy = y0 + r - offY;
            int m0 = kt + kq2*8;
            int pos = m0 - ox2;
            uint4 hq = {0u,0u,0u,0u}, lq4 = {0u,0u,0u,0u};
            if (yy >= 0 && yy < inH) {
                const u16* hr = hP + (size_t)yy*inW + (size_t)p*W2;
                const u16* lr = lP + (size_t)yy*inW + (size_t)p*W2;
                if (pos >= 0 && pos + 8 <= W2) {
                    if (al16) {
                        hq  = *(const uint4*)(hr + pos);
                        lq4 = *(const uint4*)(lr + pos);
                    } else {
                        hq.x = *(const u32*)(hr+pos);   hq.y = *(const u32*)(hr+pos+2);
                        hq.z = *(const u32*)(hr+pos+4); hq.w = *(const u32*)(hr+pos+6);
                        lq4.x = *(const u32*)(lr+pos);   lq4.y = *(const u32*)(lr+pos+2);
                        lq4.z = *(const u32*)(lr+pos+4); lq4.w = *(const u32*)(lr+pos+6);
                    }
                } else if (pos + 8 > 0 && pos < W2) {
#pragma unroll
                    for (int q = 0; q < 4; ++q) {
                        int pp = pos + 2*q;
                        if (pp >= 0 && pp + 2 <= W2) {
                            ((u32*)&hq)[q]  = *(const u32*)(hr+pp);
                            ((u32*)&lq4)[q] = *(const u32*)(lr+pp);
                        }
                    }
                }
            }
            int base = ((r >> 4)*64 + (r & 15) + 16*kq2)*8;
            *(uint4*)&AhS[p][base] = hq;
            *(uint4*)&AlS[p][base] = lq4;
        }
        __syncthreads();
        short8 A0h[2], A0l[2], A1h[2], A1l[2];
#pragma unroll
        for (int mi = 0; mi < 2; ++mi) {
            int fo = ((wave*2 + mi)*64 + lane)*8;
            A0h[mi] = *(const short8*)&AhS[0][fo];
            A0l[mi] = *(const short8*)&AlS[0][fo];
            A1h[mi] = *(const short8*)&AhS[1][fo];
            A1l[mi] = *(const short8*)&AlS[1][fo];
        }
#pragma unroll
        for (int nj = 0; nj < 4; ++nj) {
            if (nj >= njN) continue;
            size_t toff = (size_t)(col0 + nj*16 + lm)*192 + kt + lq*8;
            short8 Bh = *(const short8*)(TH + toff);
            short8 Bl = *(const short8*)(TL + toff);
#pragma unroll
            for (int mi = 0; mi < 2; ++mi) {
                accA[mi][nj] = __builtin_amdgcn_mfma_f32_16x16x32_bf16(A0h[mi], Bh, accA[mi][nj], 0, 0, 0);
                accA[mi][nj] = __builtin_amdgcn_mfma_f32_16x16x32_bf16(A0h[mi], Bl, accA[mi][nj], 0, 0, 0);
                accA[mi][nj] = __builtin_amdgcn_mfma_f32_16x16x32_bf16(A0l[mi], Bh, accA[mi][nj], 0, 0, 0);
                accB[mi][nj] = __builtin_amdgcn_mfma_f32_16x16x32_bf16(A1h[mi], Bh, accB[mi][nj], 0, 0, 0);
                accB[mi][nj] = __builtin_amdgcn_mfma_f32_16x16x32_bf16(A1h[mi], Bl, accB[mi][nj], 0, 0, 0);
                accB[mi][nj] = __builtin_amdgcn_mfma_f32_16x16x32_bf16(A1l[mi], Bh, accB[mi][nj], 0, 0, 0);
            }
        }
        __syncthreads();
    }
    r2c192_epilogue(accA, accB, col0, njN, y0, wave, lm, lq, twT, outp, B, plane);
}

// ---------------- lse combine ----------------
__device__ __forceinline__ void lse_comb(float& m, float& s, float m2, float s2)
{
    if (m2 > m) { s = s * expf(m - m2) + s2; m = m2; }
    else        { s = s + s2 * expf(m2 - m); }
}

// ---------------- radix-2 MFMA row pass C2R (raw spectrum; gpm fused into staging) ------
// Staging computes G+ (p=0) / G- (p=1) inline from the Hermitian pair - bit-identical
// to the old standalone gpm pre-pass. Ain is read-only now.
// FUSE_LSE instantiation adds per-block LSE partials (used only for the kernel image).
template<bool FUSE_LSE>
__global__ __launch_bounds__(256) void c2r192(
    const uint2* __restrict__ Ain,
    const u16* __restrict__ UH, const u16* __restrict__ UL,
    float* __restrict__ outp, const float* __restrict__ thr,
    u16* __restrict__ spH, u16* __restrict__ spL, int B,
    float2* __restrict__ parts, const float2* __restrict__ twT)
{
    __shared__ u16 AhS[2][8*64*8];
    __shared__ u16 AlS[2][8*64*8];
    int col0 = blockIdx.x * 64;      // m-tile
    int y0   = blockIdx.y * 128;
    int plane = blockIdx.z;
    int tid = threadIdx.x;
    int wave = tid >> 6, lane = tid & 63;
    int lm = lane & 15, lq = lane >> 4;
    f32x4 accP[2][4], accQ[2][4];
#pragma unroll
    for (int mi = 0; mi < 2; ++mi)
#pragma unroll
        for (int nj = 0; nj < 4; ++nj) {
            accP[mi][nj] = (f32x4){0.f,0.f,0.f,0.f};
            accQ[mi][nj] = (f32x4){0.f,0.f,0.f,0.f};
        }
    for (int kt = 0; kt < 194; kt += 32) {
#pragma unroll
        for (int s = 0; s < 8; ++s) {
            int slot = tid + s*256;
            int p   = slot >> 10;
            int inr = slot & 1023;
            int r = inr >> 3, kq = inr & 7;
            size_t rowb = ((size_t)(y0 + r)*B + plane)*KF;
            int j0 = (kt + kq*4) >> 1;   // always even
            uint2 u0, u1;
            u0.x = u0.y = u1.x = u1.y = 0u;
            if (j0 < 96) {               // j0 even <= 94 => j0+1 <= 95 < 96
                float2 f1 = ldc(Ain, rowb + j0);
                float2 f2 = ldc(Ain, rowb + 192 - j0);
                float2 g1 = ldc(Ain, rowb + j0 + 1);
                float2 g2 = ldc(Ain, rowb + 191 - j0);
                if (p == 0) {
                    u0 = packc(f1.x + f2.x, f1.y - f2.y);
                    u1 = packc(g1.x + g2.x, g1.y - g2.y);
                } else {
                    float hx = f1.x - f2.x, hy = f1.y + f2.y;
                    float2 tw = twT[j0];
                    u0 = packc(tw.x*hx - tw.y*hy, tw.x*hy + tw.y*hx);
                    hx = g1.x - g2.x; hy = g1.y + g2.y;
                    tw = twT[j0 + 1];
                    u1 = packc(tw.x*hx - tw.y*hy, tw.x*hy + tw.y*hx);
                }
            } else if (j0 == 96) {
                float2 f = ldc(Ain, rowb + 96);
                float v = (p == 0) ? 2.f*f.x : -2.f*f.y;
                u16 h = bf16_rn(v);
                u0.x = h; u0.y = bf16_rn(v - bf16_to_f(h));
            }
            int base = ((r >> 4)*64 + (r & 15) + 16*(kq >> 1))*8 + (kq & 1)*4;
            uint2 hp, lp;
            hp.x = u0.x; hp.y = u1.x;
            lp.x = u0.y; lp.y = u1.y;
            *(uint2*)&AhS[p][base] = hp;
            *(uint2*)&AlS[p][base] = lp;
        }
        __syncthreads();
        short8 A0h[2], A0l[2], A1h[2], A1l[2];
#pragma unroll
        for (int mi = 0; mi < 2; ++mi) {
            int fo = ((wave*2 + mi)*64 + lane)*8;
            A0h[mi] = *(const short8*)&AhS[0][fo];
            A0l[mi] = *(const short8*)&AlS[0][fo];
            A1h[mi] = *(const short8*)&AhS[1][fo];
            A1l[mi] = *(const short8*)&AlS[1][fo];
        }
#pragma unroll
        for (int nj = 0; nj < 4; ++nj) {
            size_t toff = (size_t)(col0 + nj*16 + lm)*224 + kt + lq*8;
            short8 Bh = *(const short8*)(UH + toff);
            short8 Bl = *(const short8*)(UL + toff);
#pragma unroll
            for (int mi = 0; mi < 2; ++mi) {
                accP[mi][nj] = __builtin_amdgcn_mfma_f32_16x16x32_bf16(A0h[mi], Bh, accP[mi][nj], 0, 0, 0);
                accP[mi][nj] = __builtin_amdgcn_mfma_f32_16x16x32_bf16(A0h[mi], Bl, accP[mi][nj], 0, 0, 0);
                accP[mi][nj] = __builtin_amdgcn_mfma_f32_16x16x32_bf16(A0l[mi], Bh, accP[mi][nj], 0, 0, 0);
                accQ[mi][nj] = __builtin_amdgcn_mfma_f32_16x16x32_bf16(A1h[mi], Bh, accQ[mi][nj], 0, 0, 0);
                accQ[mi][nj] = __builtin_amdgcn_mfma_f32_16x16x32_bf16(A1h[mi], Bl, accQ[mi][nj], 0, 0, 0);
                accQ[mi][nj] = __builtin_amdgcn_mfma_f32_16x16x32_bf16(A1l[mi], Bh, accQ[mi][nj], 0, 0, 0);
            }
        }
        __syncthreads();
    }
    float bthr = thr ? thr[plane & 15] : 0.f;
    float lm_ = -1e30f, ls_ = 0.f;
#pragma unroll
    for (int mi = 0; mi < 2; ++mi) {
#pragma unroll
        for (int nj = 0; nj < 4; ++nj) {
            int m = col0 + nj*16 + lm;
#pragma unroll
            for (int rr = 0; rr < 4; ++rr) {
                int y = y0 + wave*32 + mi*16 + lq*4 + rr;
                float xe = accP[mi][nj][rr];
                float xo = accQ[mi][nj][rr];
                float2 o2; o2.x = xe; o2.y = xo;
                *(float2*)&outp[((size_t)plane*FH + y)*FH + 2*m] = o2;
                if (spH) {
                    float s0 = softt(xe, bthr), s1 = softt(xo, bthr);
                    u16 h0 = bf16_rn(s0), h1 = bf16_rn(s1);
                    u16 l0 = bf16_rn(s0 - bf16_to_f(h0)), l1 = bf16_rn(s1 - bf16_to_f(h1));
                    size_t d = (size_t)plane*SPW + (size_t)y*FH + m;
                    spH[d]       = h0; spL[d]       = l0;
                    spH[d + 192] = h1; spL[d + 192] = l1;
                }
                if (FUSE_LSE) {
                    lse_comb(lm_, ls_, 100.f*xe, 1.f);
                    lse_comb(lm_, ls_, 100.f*xo, 1.f);
                }
            }
        }
    }
    if (FUSE_LSE) {
        __shared__ float sm[256], ss[256];
        sm[tid] = lm_; ss[tid] = ls_;
        __syncthreads();
        for (int st = 128; st > 0; st >>= 1) {
            if (tid < st) {
                float mm = sm[tid], sc = ss[tid];
                lse_comb(mm, sc, sm[tid+st], ss[tid+st]);
                sm[tid] = mm; ss[tid] = sc;
            }
            __syncthreads();
        }
        if (tid == 0) {
            float2 o; o.x = sm[0]; o.y = ss[0];
            parts[plane*9 + blockIdx.y*3 + blockIdx.x] = o;
        }
    }
}

// ---------------- MFMA col pass, radix-8 DIT (standalone) ----------------
// 384-pt DFT over rows n=8m+p: C_p = 48-pt DFT of x[8m+p] (shared E48, K=96 stacked).
// X[h0+48q] = sum_p (C_p(h0) * W^(p*h0)) * w8^(pq), fused 8-pt butterfly in fp32 epilogue.
// 384 threads (6 waves x 16 rows = all 96 stacked rows), 1D grid; N-tile 32.
__global__ __launch_bounds__(384) void zgemm_col_mfma8(
    const u16* __restrict__ EH, const u16* __restrict__ EL,
    const uint2* __restrict__ Bm, uint2* __restrict__ Cm, int N, float sgn,
    int ktHi, const float2* __restrict__ twT)
{
    __shared__ u16 BhS[8][2*64*8];
    __shared__ u16 BlS[8][2*64*8];
    int col0 = blockIdx.x * 32;
    int tid = threadIdx.x;
    int wave = tid >> 6, lane = tid & 63;
    int lm = lane & 15, lq = lane >> 4;
    f32x4 acc[8][2];
#pragma unroll
    for (int p = 0; p < 8; ++p)
#pragma unroll
        for (int nj = 0; nj < 2; ++nj)
            acc[p][nj] = (f32x4){0.f,0.f,0.f,0.f};
    int arow = wave*16 + lm;   // [0,96)
    for (int kt = 0; kt < ktHi; kt += 32) {
        int tbase = kt >> 1;
#pragma unroll
        for (int s = 0; s < 6; ++s) {
            int slot = tid + s*384;
            if (slot < 2048) {
                int p    = slot >> 8;
                int inr  = slot & 255;
                int pair = inr >> 5;
                int n    = inr & 31;
                int gn   = col0 + n;
                int t0   = tbase + pair*2;
                uint2 u0, u1;
                u0.x = u0.y = u1.x = u1.y = 0u;
                if (gn < N) {
                    u0 = Bm[(size_t)(8*t0 + p)*N + gn];
                    u1 = Bm[(size_t)(8*t0 + 8 + p)*N + gn];
                }
                int ntile = n >> 4, n0 = n & 15;
                int lrow  = (pair >> 1)*16 + n0;
                int base  = (ntile*64 + lrow)*8 + (pair & 1)*4;
                uint2 hp, lp;
                hp.x = u0.x; hp.y = u1.x;
                lp.x = u0.y; lp.y = u1.y;
                *(uint2*)&BhS[p][base] = hp;
                *(uint2*)&BlS[p][base] = lp;
            }
        }
        __syncthreads();
        short8 Ah, Al;
        {
            size_t aoff = (size_t)arow*96 + kt + lq*8;
            Ah = *(const short8*)(EH + aoff);
            Al = *(const short8*)(EL + aoff);
        }
#pragma unroll
        for (int nj = 0; nj < 2; ++nj) {
#pragma unroll
            for (int p = 0; p < 8; ++p) {
                short8 Bh = *(const short8*)&BhS[p][(nj*64 + lane)*8];
                short8 Bl = *(const short8*)&BlS[p][(nj*64 + lane)*8];
                acc[p][nj] = __builtin_amdgcn_mfma_f32_16x16x32_bf16(Ah, Bh, acc[p][nj], 0, 0, 0);
                acc[p][nj] = __builtin_amdgcn_mfma_f32_16x16x32_bf16(Ah, Bl, acc[p][nj], 0, 0, 0);
                acc[p][nj] = __builtin_amdgcn_mfma_f32_16x16x32_bf16(Al, Bh, acc[p][nj], 0, 0, 0);
            }
        }
        __syncthreads();
    }
#pragma unroll
    for (int nj = 0; nj < 2; ++nj) {
        int coln = col0 + nj*16 + lm;
        if (coln < N) {
            int r0 = wave*16 + lq*4;
            int h0b = r0 >> 1;
#pragma unroll
            for (int pp = 0; pp < 2; ++pp) {
                int h0 = h0b + pp;    // [0,48)
                float2 cc[8];
#pragma unroll
                for (int p = 0; p < 8; ++p) {
                    cc[p].x = acc[p][nj][2*pp]; cc[p].y = acc[p][nj][2*pp+1];
                }
                float2 X[8];
                bfly8(cc, h0, sgn, twT, X);
#pragma unroll
                for (int q = 0; q < 8; ++q) {
                    int row = h0 + 48*q;
                    Cm[(size_t)row*N + coln] = packc(X[q].x, X[q].y);
                }
            }
        }
    }
}

// ---------------- FUSED: forward col pass + fg update + inverse col pass ----------------
// Forward (EH/EL, sgn=-1) of Bm -> Ffy written; fg(Fz,Ffy,Fk) computed per output and
// parked in registers (bit-identical to the old FzFg store); inverse (IH/IL, sgn=+1)
// staged register->LDS (scatter by row->(p=row&7, t=row>>3)) and written back into Bm.
// Bm is read fully (barrier-drained) before its columns are overwritten; columns are
// block-disjoint, so in-place is safe.
__global__ __launch_bounds__(384) void zgemm_fg_inv(
    const u16* __restrict__ EH, const u16* __restrict__ EL,
    const u16* __restrict__ IH, const u16* __restrict__ IL,
    uint2* __restrict__ Bm, uint2* __restrict__ Ffy,
    const uint2* __restrict__ FzB, const uint2* __restrict__ FkB,
    const float* __restrict__ zet16, int N, int GKF,
    const float2* __restrict__ twT)
{
    __shared__ u16 BhS[8][2*64*8];
    __shared__ u16 BlS[8][2*64*8];
    int col0 = blockIdx.x * 32;
    int tid = threadIdx.x;
    int wave = tid >> 6, lane = tid & 63;
    int lm = lane & 15, lq = lane >> 4;
    int arow = wave*16 + lm;   // [0,96)
    // ---------------- forward ----------------
    f32x4 acc[8][2];
#pragma unroll
    for (int p = 0; p < 8; ++p)
#pragma unroll
        for (int nj = 0; nj < 2; ++nj)
            acc[p][nj] = (f32x4){0.f,0.f,0.f,0.f};
    for (int kt = 0; kt < 96; kt += 32) {
        int tbase = kt >> 1;
#pragma unroll
        for (int s = 0; s < 6; ++s) {
            int slot = tid + s*384;
            if (slot < 2048) {
                int p    = slot >> 8;
                int inr  = slot & 255;
                int pair = inr >> 5;
                int n    = inr & 31;
                int gn   = col0 + n;
                int t0   = tbase + pair*2;
                uint2 u0, u1;
                u0.x = u0.y = u1.x = u1.y = 0u;
                if (gn < N) {
                    u0 = Bm[(size_t)(8*t0 + p)*N + gn];
                    u1 = Bm[(size_t)(8*t0 + 8 + p)*N + gn];
                }
                int ntile = n >> 4, n0 = n & 15;
                int lrow  = (pair >> 1)*16 + n0;
                int base  = (ntile*64 + lrow)*8 + (pair & 1)*4;
                uint2 hp, lp;
                hp.x = u0.x; hp.y = u1.x;
                lp.x = u0.y; lp.y = u1.y;
                *(uint2*)&BhS[p][base] = hp;
                *(uint2*)&BlS[p][base] = lp;
            }
        }
        __syncthreads();
        short8 Ah, Al;
        {
            size_t aoff = (size_t)arow*96 + kt + lq*8;
            Ah = *(const short8*)(EH + aoff);
            Al = *(const short8*)(EL + aoff);
        }
#pragma unroll
        for (int nj = 0; nj < 2; ++nj) {
#pragma unroll
            for (int p = 0; p < 8; ++p) {
                short8 Bh = *(const short8*)&BhS[p][(nj*64 + lane)*8];
                short8 Bl = *(const short8*)&BlS[p][(nj*64 + lane)*8];
                acc[p][nj] = __builtin_amdgcn_mfma_f32_16x16x32_bf16(Ah, Bh, acc[p][nj], 0, 0, 0);
                acc[p][nj] = __builtin_amdgcn_mfma_f32_16x16x32_bf16(Ah, Bl, acc[p][nj], 0, 0, 0);
                acc[p][nj] = __builtin_amdgcn_mfma_f32_16x16x32_bf16(Al, Bh, acc[p][nj], 0, 0, 0);
            }
        }
        __syncthreads();
    }
    // ---------------- fwd epilogue: butterfly + Ffy write + fg -> parked pg ----------------
    int r0 = wave*16 + lq*4;
    int h0b = r0 >> 1;
    uint2 pg[2][2][8];
#pragma unroll
    for (int nj = 0; nj < 2; ++nj)
#pragma unroll
        for (int pp = 0; pp < 2; ++pp)
#pragma unroll
            for (int q = 0; q < 8; ++q) { pg[nj][pp][q].x = 0u; pg[nj][pp][q].y = 0u; }
#pragma unroll
    for (int nj = 0; nj < 2; ++nj) {
        int coln = col0 + nj*16 + lm;
        if (coln < N) {
            int planeI = coln / KF;
            int kk = coln - planeI*KF;
            int imgI = planeI >> 4;
            float zeta = 10.f * zet16[planeI & 15];
#pragma unroll
            for (int pp = 0; pp < 2; ++pp) {
                int h0 = h0b + pp;    // [0,48)
                float2 cc[8];
#pragma unroll
                for (int p = 0; p < 8; ++p) {
                    cc[p].x = acc[p][nj][2*pp]; cc[p].y = acc[p][nj][2*pp+1];
                }
                float2 X[8];
                bfly8(cc, h0, -1.f, twT, X);
#pragma unroll
                for (int q = 0; q < 8; ++q) {
                    int row = h0 + 48*q;
                    uint2 px = packc(X[q].x, X[q].y);
                    Ffy[(size_t)row*N + coln] = px;
                    float2 fy = ldcu(px);
                    float2 fz = ldc(FzB, (size_t)row*N + coln);
                    float2 fk = ldc(FkB, (size_t)row*GKF + imgI*KF + kk);
                    float nx = zeta*(fk.x*fy.x + fk.y*fy.y) + fz.x;
                    float ny = zeta*(fk.x*fy.y - fk.y*fy.x) + fz.y;
                    float den = zeta*(fk.x*fk.x + fk.y*fk.y) + 1.f + 1e-8f;
                    float inv = 1.f/den;
                    pg[nj][pp][q] = packc(nx*inv, ny*inv);
                }
            }
        }
    }
    // ---------------- inverse: 3 LDS-staged K-steps ----------------
    f32x4 iacc[8][2];
#pragma unroll
    for (int p = 0; p < 8; ++p)
#pragma unroll
        for (int nj = 0; nj < 2; ++nj)
            iacc[p][nj] = (f32x4){0.f,0.f,0.f,0.f};
    for (int s = 0; s < 3; ++s) {
        __syncthreads();   // previous step's LDS reads (or fwd) complete before overwrite
        // scatter parked pg into the staging layout: row -> (p=row&7, t=row>>3)
#pragma unroll
        for (int nj = 0; nj < 2; ++nj) {
#pragma unroll
            for (int pp = 0; pp < 2; ++pp) {
                int h0 = h0b + pp;
                int dd = h0 >> 3;
                int p  = h0 & 7;       // (h0+48q)&7 == h0&7
#pragma unroll
                for (int q = 0; q < 8; ++q) {
                    int t = 6*q + dd;  // (h0+48q)>>3
                    if ((t >> 4) == s) {
                        int pair = (t >> 1) & 7;
                        int off  = t & 1;
                        int idx  = (nj*64 + (pair>>1)*16 + lm)*4 + (pair&1)*2 + off;
                        ((u32*)BhS[p])[idx] = pg[nj][pp][q].x;
                        ((u32*)BlS[p])[idx] = pg[nj][pp][q].y;
                    }
                }
            }
        }
        __syncthreads();
        short8 Ah, Al;
        {
            size_t aoff = (size_t)arow*96 + 32*s + lq*8;
            Ah = *(const short8*)(IH + aoff);
            Al = *(const short8*)(IL + aoff);
        }
#pragma unroll
        for (int nj = 0; nj < 2; ++nj) {
#pragma unroll
            for (int p = 0; p < 8; ++p) {
                short8 Bh = *(const short8*)&BhS[p][(nj*64 + lane)*8];
                short8 Bl = *(const short8*)&BlS[p][(nj*64 + lane)*8];
                iacc[p][nj] = __builtin_amdgcn_mfma_f32_16x16x32_bf16(Ah, Bh, iacc[p][nj], 0, 0, 0);
                iacc[p][nj] = __builtin_amdgcn_mfma_f32_16x16x32_bf16(Ah, Bl, iacc[p][nj], 0, 0, 0);
                iacc[p][nj] = __builtin_amdgcn_mfma_f32_16x16x32_bf16(Al, Bh, iacc[p][nj], 0, 0, 0);
            }
        }
    }
    // ---------------- inverse epilogue: butterfly (sgn=+1) -> Bm (in place) ----------------
#pragma unroll
    for (int nj = 0; nj < 2; ++nj) {
        int coln = col0 + nj*16 + lm;
        if (coln < N) {
#pragma unroll
            for (int pp = 0; pp < 2; ++pp) {
                int h0 = h0b + pp;
                float2 cc[8];
#pragma unroll
                for (int p = 0; p < 8; ++p) {
                    cc[p].x = iacc[p][nj][2*pp]; cc[p].y = iacc[p][nj][2*pp+1];
                }
                float2 X[8];
                bfly8(cc, h0, 1.f, twT, X);
#pragma unroll
                for (int q = 0; q < 8; ++q) {
                    int row = h0 + 48*q;
                    Bm[(size_t)row*N + coln] = packc(X[q].x, X[q].y);
                }
            }
        }
    }
}

// ---------------- elementwise frequency-domain updates (uint2 spectra) ----------------
__global__ void knum_kernel(const uint2* __restrict__ Fz, const uint2* __restrict__ Ffy,
                            const uint2* __restrict__ Fk, const float* __restrict__ kprox,
                            int L, int total, uint2* __restrict__ outk)
{
    int idx = blockIdx.x*256 + threadIdx.x;
    if (idx >= total) return;
    int k = idx % KF; int r = idx / KF;
    float zk = kprox[L];
    float s1x = 0.f, s1y = 0.f, s2 = 0.f;
    for (int c = 0; c < 16; ++c) {
        size_t bi = ((size_t)r*16 + c)*KF + k;
        float2 fz = ldc(Fz, bi), fy = ldc(Ffy, bi);
        s1x += fz.x*fy.x + fz.y*fy.y;
        s1y += fz.x*fy.y - fz.y*fy.x;
        s2  += fz.x*fz.x + fz.y*fz.y;
    }
    float2 fk = ldc(Fk, idx);
    float nx = zk*s1x + fk.x, ny = zk*s1y + fk.y;
    float den = zk*s2 + 1.f + 1e-8f;
    float inv = 1.f/den;
    outk[idx] = packc(nx*inv, ny*inv);
}

__global__ void zero_kernel(float* __restrict__ p, int n)
{
    int i = blockIdx.x*256 + threadIdx.x;
    if (i < n) p[i] = 0.f;
}

__global__ void kdelta_kernel(float* __restrict__ kful, int G)
{
    int t = threadIdx.x;
    if (t < G) kful[(size_t)t*FH*FH + 22*FH + 22] = 1.f;
}

// merged: final LSE reduce over 9 block-partials + threshold/normalize/write
__global__ __launch_bounds__(256) void knew_kernel(const float2* __restrict__ parts,
    const float* __restrict__ kraw0, const float* __restrict__ kb, int L,
    float* __restrict__ kful0)
{
    int img = blockIdx.x;
    const float* kraw = kraw0 + (size_t)img*FH*FH;
    float*       kful = kful0 + (size_t)img*FH*FH;
    int t = threadIdx.x;
    __shared__ float sm[16], ss[16];
    if (t < 16) {
        if (t < 9) { float2 p = parts[img*9 + t]; sm[t] = p.x; ss[t] = p.y; }
        else       { sm[t] = -1e30f; ss[t] = 0.f; }
    }
    __syncthreads();
    for (int st = 8; st > 0; st >>= 1) {
        if (t < st) {
            float mm = sm[t], sc = ss[t];
            lse_comb(mm, sc, sm[t+st], ss[t+st]);
            sm[t] = mm; ss[t] = sc;
        }
        __syncthreads();
    }
    float kmax = (sm[0] + logf(ss[0])) * 0.01f;
    float thr = 0.01f * kb[L] * kmax;
    float vs[8]; float loc = 0.f;
#pragma unroll
    for (int ii = 0; ii < 8; ++ii) {
        int i = t + ii*256;
        float v = 0.f;
        if (i < 45*45) {
            int y = i/45, x = i - y*45;
            v = fmaxf(kraw[y*FH + x] - thr, 0.f);
        }
        vs[ii] = v; loc += v;
    }
    __shared__ float sr[256];
    sr[t] = loc; __syncthreads();
    for (int st = 128; st > 0; st >>= 1) { if (t < st) sr[t] += sr[t+st]; __syncthreads(); }
    float den = sr[0] + 1e-8f;
#pragma unroll
    for (int ii = 0; ii < 8; ++ii) {
        int i = t + ii*256;
        if (i < 45*45) {
            int y = i/45, x = i - y*45;
            float v = vs[ii] + ((y == 22 && x == 22) ? 1e-8f : 0.f);
            kful[y*FH + x] = v / den;
        }
    }
}

// ---------------- Fw0 (direct 9-term DFT of shifted 3x3), image-independent ----------------
__global__ void fw0_kernel(const float* __restrict__ w0c, const float2* __restrict__ Ef,
                           float2* __restrict__ Fw0)
{
    int idx = blockIdx.x*256 + threadIdx.x;
    if (idx >= 48*FH*KF) return;
    int k = idx % KF; int r = idx / KF;
    int c = r & 15; int r2 = r >> 4;
    int ci = r2 % 3; int h = r2 / 3;
    float accx = 0.f, accy = 0.f;
#pragma unroll
    for (int ky = 0; ky < 3; ++ky) {
        int a1 = ky - 1; if (a1 < 0) a1 += FH;
        float2 e1 = Ef[h*FH + a1];
#pragma unroll
        for (int kx = 0; kx < 3; ++kx) {
            int a2 = kx - 1; if (a2 < 0) a2 += FH;
            float2 e2 = Ef[k*FH + a2];
            float wv = w0c[((c*3 + ci)*3 + ky)*3 + kx];
            float tr = e1.x*e2.x - e1.y*e2.y;
            float ti = e1.x*e2.y + e1.y*e2.x;
            accx += wv*tr; accy += wv*ti;
        }
    }
    float2 o; o.x = accx; o.y = accy;
    Fw0[idx] = o;
}

// ---------------- final per-bin 3x3 Hermitian Wiener solve (uint2 spectra) ----------------
__global__ void wiener_kernel(const uint2* __restrict__ Fk, const uint2* __restrict__ Fy,
    const float2* __restrict__ Fw0, const uint2* __restrict__ Fg2,
    const float* __restrict__ eta, int G, int total, uint2* __restrict__ Fx)
{
    int idx = blockIdx.x*256 + threadIdx.x;
    if (idx >= total) return;
    int k = idx % KF; int r = idx / KF;
    int h = r / G;
    float2 fk = ldc(Fk, idx);
    float fksq = fk.x*fk.x + fk.y*fk.y;
    float2 fyr = ldc(Fy, ((size_t)3*r + 0)*KF + k);
    float2 fyg = ldc(Fy, ((size_t)3*r + 1)*KF + k);
    float2 fyb = ldc(Fy, ((size_t)3*r + 2)*KF + k);
    float Crr = fksq, Cgg = fksq, Cbb = fksq;
    float2 Crg, Crb, Cgb;
    Crg.x = Crg.y = Crb.x = Crb.y = Cgb.x = Cgb.y = 0.f;
    float2 Br, Bg, Bb;
    Br.x = fk.x*fyr.x + fk.y*fyr.y; Br.y = fk.x*fyr.y - fk.y*fyr.x;
    Bg.x = fk.x*fyg.x + fk.y*fyg.y; Bg.y = fk.x*fyg.y - fk.y*fyg.x;
    Bb.x = fk.x*fyb.x + fk.y*fyb.y; Bb.y = fk.x*fyb.y - fk.y*fyb.x;
    for (int c = 0; c < 16; ++c) {
        float es = 10.f * eta[c];
        float2 wr = Fw0[((size_t)h*48 +  0 + c)*KF + k];
        float2 wg = Fw0[((size_t)h*48 + 16 + c)*KF + k];
        float2 wb = Fw0[((size_t)h*48 + 32 + c)*KF + k];
        float2 g  = ldc(Fg2, ((size_t)r*16 + c)*KF + k);
        Crr += es*(wr.x*wr.x + wr.y*wr.y);
        Cgg += es*(wg.x*wg.x + wg.y*wg.y);
        Cbb += es*(wb.x*wb.x + wb.y*wb.y);
        Crg.x += es*(wr.x*wg.x + wr.y*wg.y); Crg.y += es*(wr.x*wg.y - wr.y*wg.x);
        Crb.x += es*(wr.x*wb.x + wr.y*wb.y); Crb.y += es*(wr.x*wb.y - wr.y*wb.x);
        Cgb.x += es*(wg.x*wb.x + wg.y*wb.y); Cgb.y += es*(wg.x*wb.y - wg.y*wb.x);
        Br.x += es*(wr.x*g.x + wr.y*g.y); Br.y += es*(wr.x*g.y - wr.y*g.x);
        Bg.x += es*(wg.x*g.x + wg.y*g.y); Bg.y += es*(wg.x*g.y - wg.y*g.x);
        Bb.x += es*(wb.x*g.x + wb.y*g.y); Bb.y += es*(wb.x*g.y - wb.y*g.x);
    }
    float Crg_sq = Crg.x*Crg.x + Crg.y*Crg.y;
    float Crb_sq = Crb.x*Crb.x + Crb.y*Crb.y;
    float Cgb_sq = Cgb.x*Cgb.x + Cgb.y*Cgb.y;
    float Irr = Cgg*Cbb - Cgb_sq;
    float Igg = Crr*Cbb - Crb_sq;
    float Ibb = Crr*Cgg - Crg_sq;
    float2 Irg, Irb, Igb;
    Irg.x = (Cgb.x*Crb.x + Cgb.y*Crb.y) - Cbb*Crg.x;
    Irg.y = (Cgb.x*Crb.y - Cgb.y*Crb.x) - Cbb*Crg.y;
    Irb.x = (Crg.x*Cgb.x - Crg.y*Cgb.y) - Cgg*Crb.x;
    Irb.y = (Crg.x*Cgb.y + Crg.y*Cgb.x) - Cgg*Crb.y;
    Igb.x = (Crg.x*Crb.x + Crg.y*Crb.y) - Crr*Cgb.x;
    Igb.y = (Crg.x*Crb.y - Crg.y*Crb.x) - Crr*Cgb.y;
    float tx_ = Crg.x*Cgb.x - Crg.y*Cgb.y;
    float ty_ = Crg.x*Cgb.y + Crg.y*Cgb.x;
    float den = Crr*Irr - Cgg*Crb_sq - Cbb*Crg_sq + 2.f*(tx_*Crb.x + ty_*Crb.y) + 1e-8f;
    float inv = 1.f/den;
    float ox, oy;
    ox = (Irr*Br.x + (Irg.x*Bg.x - Irg.y*Bg.y) + (Irb.x*Bb.x - Irb.y*Bb.y))*inv;
    oy = (Irr*Br.y + (Irg.x*Bg.y + Irg.y*Bg.x) + (Irb.x*Bb.y + Irb.y*Bb.x))*inv;
    Fx[((size_t)3*r + 0)*KF + k] = packc(ox, oy);
    ox = ((Irg.x*Br.x + Irg.y*Br.y) + Igg*Bg.x + (Igb.x*Bb.x - Igb.y*Bb.y))*inv;
    oy = ((Irg.x*Br.y - Irg.y*Br.x) + Igg*Bg.y + (Igb.x*Bb.y + Igb.y*Bb.x))*inv;
    Fx[((size_t)3*r + 1)*KF + k] = packc(ox, oy);
    ox = ((Irb.x*Br.x + Irb.y*Br.y) + (Igb.x*Bg.x + Igb.y*Bg.y) + Ibb*Bb.x)*inv;
    oy = ((Irb.x*Br.y - Irb.y*Br.x) + (Igb.x*Bg.y - Igb.y*Bg.x) + Ibb*Bb.y)*inv;
    Fx[((size_t)3*r + 2)*KF + k] = packc(ox, oy);
}

// ---------------- output assembly ----------------
__global__ void crop_kernel(const float* __restrict__ sp, float* __restrict__ outp, int total)
{
    int idx = blockIdx.x*256 + threadIdx.x;
    if (idx >= total) return;
    int x = idx & 255; int r = idx >> 8; int y = r & 255; int plane = r >> 8;
    outp[idx] = sp[((size_t)plane*FH + (y+22))*FH + (x+22)];
}

__global__ void kcopy_kernel(const float* __restrict__ kful, float* __restrict__ outp, int total)
{
    int idx = blockIdx.x*256 + threadIdx.x;
    if (idx >= total) return;
    int rem = idx % 2025; int img = idx / 2025;
    int x = rem % 45; int y = rem / 45;
    outp[idx] = kful[(size_t)img*FH*FH + y*FH + x];
}

// =====================================================================
extern "C" void kernel_launch(void* const* d_in, const int* in_sizes, int n_in,
                              void* d_out, int out_size, void* d_ws, size_t ws_size,
                              hipStream_t stream)
{
    (void)in_sizes; (void)n_in; (void)out_size;
    const float* blurred = (const float*)d_in[0];
    const float* w0      = (const float*)d_in[1];
    const float* wsw     = (const float*)d_in[2];
    const float* biases  = (const float*)d_in[3];
    const float* kbias   = (const float*)d_in[4];
    const float* kprox   = (const float*)d_in[5];
    const float* zetas   = (const float*)d_in[6];
    const float* eta     = (const float*)d_in[7];
    float* outp = (float*)d_out;

    auto al = [](size_t b) { return (b + 255) & ~(size_t)255; };
    auto need = [&](int G) -> size_t {
        size_t s = 0;
        s += al((size_t)FH*FH*8);                 // Ef
        s += al(384*8);                           // twT
        s += 4*al((size_t)96*96*2);               // E48 fwd/inv H/L
        s += 2*al((size_t)208*192*2);             // T192
        s += 2*al((size_t)192*224*2);             // U192
        s += al(432*4);                           // w0c
        s += 2*al((size_t)10*G*16*65536*2);       // fyH, fyL (split checkpoints)
        s += al((size_t)G*16*FH*FH*4);            // zsp fp32
        s += 2*al((size_t)G*16*SPW*2);            // zspSH, zspSL
        s += 3*al((size_t)G*16*FH*KF*8);          // mid, FzFg, Ffy (uint2)
        s += 4*al((size_t)G*FH*KF*8);             // Fk, kfA, kfB, kmid
        s += 2*al((size_t)G*FH*FH*4);             // kraw, kful
        s += 2*al((size_t)G*3*FH*KF*8);           // FyB, FxB
        s += al((size_t)G*64*8);                  // lseP
        return s;
    };
    int G = 4;
    while (G > 1 && need(G) > ws_size) G >>= 1;

    char* base = (char*)d_ws;
    size_t off = 0;
    auto alloc = [&](size_t bytes) -> void* {
        void* p = (void*)(base + off);
        off += (bytes + 255) & ~(size_t)255;
        return p;
    };
    float2* Ef   = (float2*)alloc((size_t)FH*FH*8);
    float2* twT  = (float2*)alloc(384*8);
    u16* EfH = (u16*)alloc((size_t)96*96*2);
    u16* EfL = (u16*)alloc((size_t)96*96*2);
    u16* EiH = (u16*)alloc((size_t)96*96*2);
    u16* EiL = (u16*)alloc((size_t)96*96*2);
    u16* T1H = (u16*)alloc((size_t)208*192*2);
    u16* T1L = (u16*)alloc((size_t)208*192*2);
    u16* U1H = (u16*)alloc((size_t)192*224*2);
    u16* U1L = (u16*)alloc((size_t)192*224*2);
    float*  w0cB = (float*)alloc(432*4);
    u16*    fyH  = (u16*)alloc((size_t)10*G*16*65536*2);
    u16*    fyL  = (u16*)alloc((size_t)10*G*16*65536*2);
    float*  zsp  = (float*)alloc((size_t)G*16*FH*FH*4);
    u16*    zspSH= (u16*)alloc((size_t)G*16*SPW*2);
    u16*    zspSL= (u16*)alloc((size_t)G*16*SPW*2);
    uint2*  mid  = (uint2*)alloc((size_t)G*16*FH*KF*8);
    uint2*  FzFg = (uint2*)alloc((size_t)G*16*FH*KF*8);
    uint2*  Ffy  = (uint2*)alloc((size_t)G*16*FH*KF*8);
    uint2*  Fk   = (uint2*)alloc((size_t)G*FH*KF*8);
    uint2*  kfA  = (uint2*)alloc((size_t)G*FH*KF*8);
    uint2*  kfB  = (uint2*)alloc((size_t)G*FH*KF*8);
    uint2*  kmid = (uint2*)alloc((size_t)G*FH*KF*8);
    float*  kraw = (float*)alloc((size_t)G*FH*FH*4);
    float*  kful = (float*)alloc((size_t)G*FH*FH*4);
    uint2*  FyB  = (uint2*)alloc((size_t)G*3*FH*KF*8);
    uint2*  FxB  = (uint2*)alloc((size_t)G*3*FH*KF*8);
    float2* lseP = (float2*)alloc((size_t)G*64*8);
    // Fw0 (28.45 MB) overlays fyH — dead by final stage
    float2* Fw0B = (float2*)fyH;

    // tables + weight prep (image-independent)
    init_ef_k<<<(FH*FH+255)/256, 256, 0, stream>>>(Ef);
    init_tw<<<2, 256, 0, stream>>>(twT);
    init_e48<<<(96*96+255)/256, 256, 0, stream>>>(EfH, EfL, 0);
    init_e48<<<(96*96+255)/256, 256, 0, stream>>>(EiH, EiL, 1);
    init_t192<<<(208*192+255)/256, 256, 0, stream>>>(T1H, T1L);
    init_u192<<<(192*224+255)/256, 256, 0, stream>>>(U1H, U1L);
    w0c_kernel<<<1, 64, 0, stream>>>(w0, w0cB);

    auto zgf = [&](const uint2* Bm, uint2* Cm, int Ncols) {
        zgemm_col_mfma8<<<dim3((Ncols+31)/32), 384, 0, stream>>>(
            EfH, EfL, Bm, Cm, Ncols, -1.f, 96, twT);
    };
    auto zgi = [&](const uint2* Bm, uint2* Cm, int Ncols) {
        zgemm_col_mfma8<<<dim3((Ncols+31)/32), 384, 0, stream>>>(
            EiH, EiL, Bm, Cm, Ncols, 1.f, 96, twT);
    };
    auto r2c = [&](const float* inp, int inH, int inW, int oY, int oX,
                   const float* thr, uint2* o, int B) {
        r2c192_f<<<dim3(4, 3, B), 256, 0, stream>>>(
            inp, inH, inW, inW, (size_t)inH*inW, oY, oX, thr, T1H, T1L, twT, o, B);
    };
    auto r2cs = [&](const u16* Hs, const u16* Ls, int inH, int inW, int oY, int oX,
                    uint2* o, int B) {
        r2c192_s<<<dim3(4, 3, B), 256, 0, stream>>>(
            Hs, Ls, inH, inW, oY, oX, T1H, T1L, twT, o, B);
    };
    auto c2r = [&](uint2* Ain, float* o, int B,
                   const float* thr, u16* sH, u16* sL) {
        c2r192<false><<<dim3(3, 3, B), 256, 0, stream>>>(
            Ain, U1H, U1L, o, thr, sH, sL, B, nullptr, twT);
    };
    auto c2rk = [&](uint2* Ain, float* o, int B, float2* parts) {
        c2r192<true><<<dim3(3, 3, B), 256, 0, stream>>>(
            Ain, U1H, U1L, o, nullptr, nullptr, nullptr, B, parts, twT);
    };
    // sparse kernel-image forward FFT into kmid (45x45 support).
    // Row pass writes spectra rows 0..127 (rows >=45 exact zeros).
    // Radix-8 col pass with ktHi=32 consumes data rows 8t+p <= 127 (one K-step).
    auto r2ck = [&]() {
        r2c192_f<<<dim3(4, 1, G), 256, 0, stream>>>(
            kful, 45, 45, FH, (size_t)FH*FH, 0, 0, nullptr, T1H, T1L, twT, kmid, G);
        zgemm_col_mfma8<<<dim3((G*KF+31)/32), 384, 0, stream>>>(
            EfH, EfL, kmid, Fk, G*KF, -1.f, 32, twT);
    };

    const size_t CKL = (size_t)G*16*65536;   // one split ck layer (u16 elements)

    for (int g0 = 0; g0 < 4; g0 += G) {
        const float* img = blurred + (size_t)g0*3*65536;

        // forward conv chain: split checkpoints (parity de-interleaved)
        conv3x3_kernel<<<dim3(16,16,G), 256, 0, stream>>>(
            img, nullptr, nullptr, w0cB, fyH, fyL, 3, 1, (size_t)3*65536);
        for (int l = 1; l < 10; ++l)
            conv3x3_kernel<<<dim3(16,16,G), 256, 0, stream>>>(
                nullptr, fyH + (size_t)(l-1)*CKL, fyL + (size_t)(l-1)*CKL,
                wsw + (size_t)(l-1)*2304,
                fyH + (size_t)l*CKL, fyL + (size_t)l*CKL, 16, 0, (size_t)16*65536);

        // z init (circshift + threshold b0) -> split, Fz
        int totZ = G*16*FH*FH;
        zinit_kernel<<<(totZ+255)/256, 256, 0, stream>>>(
            fyH + 9*CKL, fyL + 9*CKL, biases, zspSH, zspSL, totZ);
        r2cs(zspSH, zspSL, FH, FH, 0, 0, mid, G*16);
        zgf(mid, FzFg, G*16*KF);

        // k init = delta
        zero_kernel<<<(G*FH*FH+255)/256, 256, 0, stream>>>(kful, G*FH*FH);
        kdelta_kernel<<<1, 64, 0, stream>>>(kful, G);

        int totK = G*FH*KF;
        int NS = G*16*KF;
        for (int it = 0; it < 10; ++it) {
            int Lfy = 9 - it;
            r2ck();   // Fk first (needed by fused fg epilogue below)
            r2cs(fyH + (size_t)Lfy*CKL, fyL + (size_t)Lfy*CKL, 256, 256, 44, 44, mid, G*16);
            // FUSED: forward col pass -> Ffy, fg(Fz_old, Ffy, Fk), inverse col of Fg -> mid
            zgemm_fg_inv<<<dim3((NS+31)/32), 384, 0, stream>>>(
                EfH, EfL, EiH, EiL, mid, Ffy, FzFg, Fk, zetas + it*16, NS, G*KF, twT);
            // zsp = irfft(Fg) PRE-threshold; side-output = softt-split for next r2c
            c2r(mid, zsp, G*16, biases + (it+1)*16, zspSH, zspSL);
            r2cs(zspSH, zspSL, FH, FH, 0, 0, mid, G*16);   // pre-split, no conversions
            zgf(mid, FzFg, NS);                            // Fz_new
            knum_kernel<<<(totK+255)/256, 256, 0, stream>>>(FzFg, Ffy, Fk, kprox, it, totK, kfA);
            zgi(kfA, kfB, G*KF);
            c2rk(kfB, kraw, G, lseP);                      // + fused LSE partials
            knew_kernel<<<G, 256, 0, stream>>>(lseP, kraw, kbias, it, kful);
        }

        // ---- final stage (fyH/fyL dead; Fw0 overlay live) ----
        r2c(img, 256, 256, 44, 44, nullptr, mid, 3*G);
        zgf(mid, FyB, 3*G*KF);
        r2ck();
        // Fg2 = rfft(softt(zsp, b_final)) — from fp32 zsp with fused threshold
        r2c(zsp, FH, FH, 0, 0, biases + 11*16, mid, G*16);
        zgf(mid, FzFg, G*16*KF);
        fw0_kernel<<<(48*FH*KF+255)/256, 256, 0, stream>>>(w0cB, Ef, Fw0B);
        wiener_kernel<<<(totK+255)/256, 256, 0, stream>>>(Fk, FyB, Fw0B, FzFg, eta, G, totK, FxB);
        zgi(FxB, mid, 3*G*KF);
        c2r(mid, zsp, 3*G, nullptr, nullptr, nullptr);
        int totC = G*3*65536;
        crop_kernel<<<(totC+255)/256, 256, 0, stream>>>(zsp, outp + (size_t)g0*3*65536, totC);
        int totKC = G*2025;
        kcopy_kernel<<<(totKC+255)/256, 256, 0, stream>>>(kful, outp + 786432 + g0*2025, totKC);
    }
}

// Round 17
// 7369.325 us; speedup vs baseline: 1.4123x; 1.4123x over previous
//
#include <hip/hip_runtime.h>
#include <math.h>

#define FH 384
#define KF 193
#define SPW 147456

typedef __attribute__((ext_vector_type(8))) short short8;
typedef __attribute__((ext_vector_type(4))) float f32x4;
typedef unsigned int u32;
typedef unsigned short u16;

static __device__ __forceinline__ float softt(float v, float b) {
    return copysignf(fmaxf(fabsf(v) - b, 0.f), v);
}
static __device__ __forceinline__ u16 bf16_rn(float v) {
    u32 u = __float_as_uint(v);
    u32 r = (u + 0x7FFFu + ((u >> 16) & 1u)) >> 16;
    return (u16)r;
}
static __device__ __forceinline__ float bf16_to_f(u16 h) {
    return __uint_as_float(((u32)h) << 16);
}
// complex spectra stored as uint2: .x = H-word (bf16 re | bf16 im<<16), .y = L-word
static __device__ __forceinline__ float2 ldc(const uint2* __restrict__ S, size_t i) {
    uint2 u = S[i];
    float2 r;
    r.x = __uint_as_float((u.x & 0xffffu) << 16) + __uint_as_float((u.y & 0xffffu) << 16);
    r.y = __uint_as_float(u.x & 0xffff0000u) + __uint_as_float(u.y & 0xffff0000u);
    return r;
}
static __device__ __forceinline__ float2 ldcu(uint2 u) {
    float2 r;
    r.x = __uint_as_float((u.x & 0xffffu) << 16) + __uint_as_float((u.y & 0xffffu) << 16);
    r.y = __uint_as_float(u.x & 0xffff0000u) + __uint_as_float(u.y & 0xffff0000u);
    return r;
}
static __device__ __forceinline__ uint2 packc(float re, float im) {
    u16 hr = bf16_rn(re), hi = bf16_rn(im);
    u16 lr = bf16_rn(re - bf16_to_f(hr)), li = bf16_rn(im - bf16_to_f(hi));
    uint2 o; o.x = (u32)hr | ((u32)hi << 16); o.y = (u32)lr | ((u32)li << 16);
    return o;
}
static __device__ __forceinline__ float2 cmul(float2 a, float2 b) {
    float2 r; r.x = a.x*b.x - a.y*b.y; r.y = a.x*b.y + a.y*b.x; return r;
}

// 8-point DIT butterfly over twiddled 48-DFT partials (shared by fwd/inv col passes)
static __device__ __forceinline__ void bfly8(const float2 cc[8], int h0, float sgn,
                                             const float2* __restrict__ twT, float2 X[8])
{
    const float rt = 0.70710678118654752f;
    float2 d[8];
    d[0] = cc[0];
#pragma unroll
    for (int p = 1; p < 8; ++p) {
        float2 w = twT[p*h0];
        w.y *= sgn;
        d[p] = cmul(cc[p], w);
    }
    float2 e0, e1, e2, e3, o0, o1, o2, o3;
    e0.x = d[0].x + d[4].x; e0.y = d[0].y + d[4].y;
    e1.x = d[1].x + d[5].x; e1.y = d[1].y + d[5].y;
    e2.x = d[2].x + d[6].x; e2.y = d[2].y + d[6].y;
    e3.x = d[3].x + d[7].x; e3.y = d[3].y + d[7].y;
    o0.x = d[0].x - d[4].x; o0.y = d[0].y - d[4].y;
    o1.x = d[1].x - d[5].x; o1.y = d[1].y - d[5].y;
    o2.x = d[2].x - d[6].x; o2.y = d[2].y - d[6].y;
    o3.x = d[3].x - d[7].x; o3.y = d[3].y - d[7].y;
    float2 s02, m02, s13, m13, i13;
    s02.x = e0.x + e2.x; s02.y = e0.y + e2.y;
    m02.x = e0.x - e2.x; m02.y = e0.y - e2.y;
    s13.x = e1.x + e3.x; s13.y = e1.y + e3.y;
    m13.x = e1.x - e3.x; m13.y = e1.y - e3.y;
    i13.x = -sgn*m13.y;  i13.y = sgn*m13.x;
    X[0].x = s02.x + s13.x; X[0].y = s02.y + s13.y;
    X[4].x = s02.x - s13.x; X[4].y = s02.y - s13.y;
    X[2].x = m02.x + i13.x; X[2].y = m02.y + i13.y;
    X[6].x = m02.x - i13.x; X[6].y = m02.y - i13.y;
    float2 g0 = o0, g1, g2, g3;
    g1.x = rt*(o1.x - sgn*o1.y);  g1.y = rt*(sgn*o1.x + o1.y);       // *w8
    g2.x = -sgn*o2.y;             g2.y = sgn*o2.x;                   // *w4
    g3.x = rt*(-(o3.x + sgn*o3.y)); g3.y = rt*(sgn*o3.x - o3.y);     // *w8^3
    float2 sp, mp, sq, mq, iq;
    sp.x = g0.x + g2.x; sp.y = g0.y + g2.y;
    mp.x = g0.x - g2.x; mp.y = g0.y - g2.y;
    sq.x = g1.x + g3.x; sq.y = g1.y + g3.y;
    mq.x = g1.x - g3.x; mq.y = g1.y - g3.y;
    iq.x = -sgn*mq.y;   iq.y = sgn*mq.x;
    X[1].x = sp.x + sq.x; X[1].y = sp.y + sq.y;
    X[5].x = sp.x - sq.x; X[5].y = sp.y - sq.y;
    X[3].x = mp.x + iq.x; X[3].y = mp.y + iq.y;
    X[7].x = mp.x - iq.x; X[7].y = mp.y - iq.y;
}

// ---------------- tables ----------------
__global__ void init_ef_k(float2* Ef) {
    int idx = blockIdx.x * 256 + threadIdx.x;
    if (idx >= FH * FH) return;
    int h = idx / FH, j = idx % FH;
    int m = (h * j) % FH;
    float th = (float)(6.283185307179586 / FH) * (float)m;
    float2 v; v.x = cosf(th); v.y = -sinf(th);
    Ef[idx] = v;
}

// twiddle table: twT[h] = (cos(2*pi*h/384), sin(2*pi*h/384)), h in [0,384)
__global__ void init_tw(float2* twT) {
    int i = blockIdx.x * 256 + threadIdx.x;
    if (i < 384) {
        float th = (float)(6.283185307179586 / 384.0) * (float)i;
        float2 v; v.x = cosf(th); v.y = sinf(th);
        twT[i] = v;
    }
}

// E48: stacked-real 48-point DFT matrix (96x96), radix-8 col pass.
// Inverse bakes the FULL 1/384 scale.
__global__ void init_e48(u16* __restrict__ H, u16* __restrict__ L, int inv)
{
    int idx = blockIdx.x * 256 + threadIdx.x;
    if (idx >= 96 * 96) return;
    int gm = idx / 96, kp = idx % 96;
    int m = gm >> 1, comp = gm & 1;
    int t = kp >> 1, ri = kp & 1;
    int mm = (m * t) % 48;
    float th = (float)(6.283185307179586 / 48.0) * (float)mm;
    float c = cosf(th), s = sinf(th);
    float er, ei;
    if (inv) { er = c * (1.f/384.f); ei = s * (1.f/384.f); }
    else     { er = c;               ei = -s; }
    float v;
    if (comp == 0) v = (ri == 0) ? er : -ei;
    else           v = (ri == 0) ? ei :  er;
    u16 h = bf16_rn(v);
    H[idx] = h;
    L[idx] = bf16_rn(v - bf16_to_f(h));
}

// Tt192: row-pass forward 192-pt DFT matrix, [n:208 stacked][m:192]
__global__ void init_t192(u16* __restrict__ H, u16* __restrict__ L)
{
    int idx = blockIdx.x * 256 + threadIdx.x;
    if (idx >= 208 * 192) return;
    int n = idx / 192, m = idx % 192;
    float v = 0.f;
    if (n < 194) {
        int j = n >> 1, ri = n & 1;
        int mm = (j * m) % 192;
        float th = (float)(6.283185307179586 / 192.0) * (float)mm;
        v = ri ? -sinf(th) : cosf(th);
    }
    u16 h = bf16_rn(v);
    H[idx] = h;
    L[idx] = bf16_rn(v - bf16_to_f(h));
}

// Ut192: row-pass inverse fold matrix, [m:192][kk:224], weights 1/384 | 2/384
__global__ void init_u192(u16* __restrict__ H, u16* __restrict__ L)
{
    int idx = blockIdx.x * 256 + threadIdx.x;
    if (idx >= 192 * 224) return;
    int m = idx / 224, kk = idx % 224;
    float v = 0.f;
    if (kk < 194) {
        int j = kk >> 1, ri = kk & 1;
        float cj = (j == 0 || j == 96) ? (1.f/384.f) : (2.f/384.f);
        int mm = (j * m) % 192;
        float th = (float)(6.283185307179586 / 192.0) * (float)mm;
        v = ri ? -cj*sinf(th) : cj*cosf(th);
    }
    u16 h = bf16_rn(v);
    H[idx] = h;
    L[idx] = bf16_rn(v - bf16_to_f(h));
}

// ---------------- w0 centering ----------------
__global__ void w0c_kernel(const float* __restrict__ w0, float* __restrict__ w0c) {
    int t = threadIdx.x;
    if (t < 48) {
        float m = 0.f;
        for (int d = 0; d < 9; ++d) m += w0[t*9+d];
        m *= (1.f/9.f);
        for (int d = 0; d < 9; ++d) w0c[t*9+d] = w0[t*9+d] - m;
    }
}

// ---------------- 3x3 conv: input fp32 (first) or split H/L (de-interleaved);
// output split H/L, parity-de-interleaved rows: [even x block | odd x block] ----------------
__global__ __launch_bounds__(256) void conv3x3_kernel(
    const float* __restrict__ inpF0, const u16* __restrict__ inH0, const u16* __restrict__ inL0,
    const float* __restrict__ w,
    u16* __restrict__ outH0, u16* __restrict__ outL0, int Cin, int flip,
    size_t inImgStride)
{
    size_t iofs = (size_t)blockIdx.z * inImgStride;
    const float* inF = inpF0 ? inpF0 + iofs : nullptr;
    const u16*   iH  = inH0 ? inH0 + iofs : nullptr;
    const u16*   iL  = inL0 ? inL0 + iofs : nullptr;
    u16* oH = outH0 + (size_t)blockIdx.z * 16*65536;
    u16* oL = outL0 + (size_t)blockIdx.z * 16*65536;
    __shared__ float tile[18][19];
    __shared__ float wl[16*16*9];
    int x0 = blockIdx.x * 16, y0 = blockIdx.y * 16;
    int t = threadIdx.x;
    int tx = t & 15, ty = t >> 4;
    int nw = 16 * Cin * 9;
    for (int i = t; i < nw; i += 256) {
        int d = i % 9;
        wl[i] = flip ? w[i + 8 - 2*d] : w[i];
    }
    float acc[16];
#pragma unroll
    for (int co = 0; co < 16; ++co) acc[co] = 0.f;
    for (int ci = 0; ci < Cin; ++ci) {
        __syncthreads();
        for (int i = t; i < 18*18; i += 256) {
            int yy = i / 18, xx = i % 18;
            int gy = y0 - 1 + yy, gx = x0 - 1 + xx;
            float v = 0.f;
            if (gy >= 0 && gy < 256 && gx >= 0 && gx < 256) {
                size_t ii;
                if (inF) ii = ((size_t)ci*256 + gy)*256 + gx;
                else     ii = ((size_t)ci*256 + gy)*256 + ((gx>>1) + (gx&1)*128);
                v = inF ? inF[ii] : (bf16_to_f(iH[ii]) + bf16_to_f(iL[ii]));
            }
            tile[yy][xx] = v;
        }
        __syncthreads();
        float v[9];
#pragma unroll
        for (int dy = 0; dy < 3; dy++)
#pragma unroll
            for (int dx = 0; dx < 3; dx++) v[dy*3+dx] = tile[ty+dy][tx+dx];
#pragma unroll
        for (int co = 0; co < 16; co++) {
            const float* wp = &wl[(co*Cin+ci)*9];
            acc[co] += v[0]*wp[0]+v[1]*wp[1]+v[2]*wp[2]
                     + v[3]*wp[3]+v[4]*wp[4]+v[5]*wp[5]
                     + v[6]*wp[6]+v[7]*wp[7]+v[8]*wp[8];
        }
    }
    int xo = x0 + tx;
    int xd = (xo >> 1) + (xo & 1)*128;
#pragma unroll
    for (int co = 0; co < 16; co++) {
        size_t o = ((size_t)co*256 + (y0+ty))*256 + xd;
        u16 h = bf16_rn(acc[co]);
        oH[o] = h;
        oL[o] = bf16_rn(acc[co] - bf16_to_f(h));
    }
}

// ---------------- z init: circshift(22,22) of padded split fy9 + soft threshold,
// writes split H/L de-interleaved (FH-wide rows: [192 even | 192 odd]) ------
__global__ void zinit_kernel(const u16* __restrict__ fy9H, const u16* __restrict__ fy9L,
                             const float* __restrict__ b0,
                             u16* __restrict__ oH, u16* __restrict__ oL, int total)
{
    int idx = blockIdx.x*256 + threadIdx.x;
    if (idx >= total) return;
    int x = idx % FH; int r = idx / FH; int y = r % FH; int plane = r / FH;
    int c = plane & 15;
    int Y = y + 22; if (Y >= FH) Y -= FH;
    int X = x + 22; if (X >= FH) X -= FH;
    int yy = Y - 44, xx = X - 44;
    float v = 0.f;
    if (yy >= 0 && yy < 256 && xx >= 0 && xx < 256) {
        size_t ii = ((size_t)plane*256 + yy)*256 + ((xx>>1) + (xx&1)*128);
        v = bf16_to_f(fy9H[ii]) + bf16_to_f(fy9L[ii]);
    }
    float s = softt(v, b0[c]);
    u16 h = bf16_rn(s);
    size_t d = (size_t)plane*SPW + (size_t)y*FH + ((x>>1) + (x&1)*192);
    oH[d] = h;
    oL[d] = bf16_rn(s - bf16_to_f(h));
}

// ---------------- shared epilogue for radix-2 row R2C ----------------
static __device__ __forceinline__ void r2c192_epilogue(
    f32x4 accA[2][4], f32x4 accB[2][4],
    int col0, int njN, int y0, int wave, int lm, int lq,
    const float2* __restrict__ twT,
    uint2* __restrict__ outp, int B, int plane)
{
#pragma unroll
    for (int mi = 0; mi < 2; ++mi) {
#pragma unroll
        for (int nj = 0; nj < 4; ++nj) {
            if (nj >= njN) continue;
            int n = col0 + nj*16 + lm;
            int j = n >> 1;
            float pA[4], pB[4];
#pragma unroll
            for (int rr = 0; rr < 4; ++rr) {
                pA[rr] = __shfl_xor(accA[mi][nj][rr], 1);
                pB[rr] = __shfl_xor(accB[mi][nj][rr], 1);
            }
            if (((lm & 1) == 0) && j <= 96) {
                float2 tw = twT[j];
                float wr = tw.x, wi = -tw.y;
                int ybase = y0 + wave*32 + mi*16 + lq*4;
#pragma unroll
                for (int rr = 0; rr < 4; ++rr) {
                    float ar = accA[mi][nj][rr], ai = pA[rr];
                    float br = accB[mi][nj][rr], bi = pB[rr];
                    float tr = wr*br - wi*bi;
                    float ti = wr*bi + wi*br;
                    size_t rowb = ((size_t)(ybase+rr)*B + plane)*KF;
                    outp[rowb + j] = packc(ar + tr, ai + ti);
                    if (j < 96) outp[rowb + 192 - j] = packc(ar - tr, -(ai - ti));
                }
            }
        }
    }
}

// ---------------- radix-2 MFMA row pass R2C (fp32 source, fused softt) ----------------
__global__ __launch_bounds__(256) void r2c192_f(
    const float* __restrict__ inp, int inH, int inW, int inStride, size_t planeStride,
    int offY, int offX,
    const float* __restrict__ thr,
    const u16* __restrict__ TH, const u16* __restrict__ TL,
    const float2* __restrict__ twT,
    uint2* __restrict__ outp, int B)
{
    __shared__ u16 AhS[2][8*64*8];
    __shared__ u16 AlS[2][8*64*8];
    int col0 = blockIdx.x * 64;
    int y0   = blockIdx.y * 128;
    int plane = blockIdx.z;
    int njN = (col0 >= 192) ? 1 : 4;
    int tid = threadIdx.x;
    int wave = tid >> 6, lane = tid & 63;
    int lm = lane & 15, lq = lane >> 4;
    f32x4 accA[2][4], accB[2][4];
#pragma unroll
    for (int mi = 0; mi < 2; ++mi)
#pragma unroll
        for (int nj = 0; nj < 4; ++nj) {
            accA[mi][nj] = (f32x4){0.f,0.f,0.f,0.f};
            accB[mi][nj] = (f32x4){0.f,0.f,0.f,0.f};
        }
    float bthr = thr ? thr[plane & 15] : 0.f;
    const float* inpP = inp + (size_t)plane*planeStride;
    int mhi = (offX + inW) >> 1;   // offX even
    for (int kt = 0; kt < mhi; kt += 32) {
#pragma unroll
        for (int s = 0; s < 4; ++s) {
            int slot = tid + s*256;
            int r = slot >> 3, kq = slot & 7;
            int yy = y0 + r - offY;
            int xx0 = 2*(kt + kq*4) - offX;
            float v[8];
#pragma unroll
            for (int d = 0; d < 8; ++d) {
                int xx = xx0 + d;
                float t = 0.f;
                if (yy >= 0 && yy < inH && xx >= 0 && xx < inW)
                    t = inpP[(size_t)yy*inStride + xx];
                if (thr) t = softt(t, bthr);
                v[d] = t;
            }
            u16 h[8], l[8];
#pragma unroll
            for (int d = 0; d < 8; ++d) {
                h[d] = bf16_rn(v[d]);
                l[d] = bf16_rn(v[d] - bf16_to_f(h[d]));
            }
            int base = ((r >> 4)*64 + (r & 15) + 16*(kq >> 1))*8 + (kq & 1)*4;
            uint2 w;
            w.x = (u32)h[0] | ((u32)h[2] << 16); w.y = (u32)h[4] | ((u32)h[6] << 16);
            *(uint2*)&AhS[0][base] = w;
            w.x = (u32)h[1] | ((u32)h[3] << 16); w.y = (u32)h[5] | ((u32)h[7] << 16);
            *(uint2*)&AhS[1][base] = w;
            w.x = (u32)l[0] | ((u32)l[2] << 16); w.y = (u32)l[4] | ((u32)l[6] << 16);
            *(uint2*)&AlS[0][base] = w;
            w.x = (u32)l[1] | ((u32)l[3] << 16); w.y = (u32)l[5] | ((u32)l[7] << 16);
            *(uint2*)&AlS[1][base] = w;
        }
        __syncthreads();
        short8 A0h[2], A0l[2], A1h[2], A1l[2];
#pragma unroll
        for (int mi = 0; mi < 2; ++mi) {
            int fo = ((wave*2 + mi)*64 + lane)*8;
            A0h[mi] = *(const short8*)&AhS[0][fo];
            A0l[mi] = *(const short8*)&AlS[0][fo];
            A1h[mi] = *(const short8*)&AhS[1][fo];
            A1l[mi] = *(const short8*)&AlS[1][fo];
        }
#pragma unroll
        for (int nj = 0; nj < 4; ++nj) {
            if (nj >= njN) continue;
            size_t toff = (size_t)(col0 + nj*16 + lm)*192 + kt + lq*8;
            short8 Bh = *(const short8*)(TH + toff);
            short8 Bl = *(const short8*)(TL + toff);
#pragma unroll
            for (int mi = 0; mi < 2; ++mi) {
                accA[mi][nj] = __builtin_amdgcn_mfma_f32_16x16x32_bf16(A0h[mi], Bh, accA[mi][nj], 0, 0, 0);
                accA[mi][nj] = __builtin_amdgcn_mfma_f32_16x16x32_bf16(A0h[mi], Bl, accA[mi][nj], 0, 0, 0);
                accA[mi][nj] = __builtin_amdgcn_mfma_f32_16x16x32_bf16(A0l[mi], Bh, accA[mi][nj], 0, 0, 0);
                accB[mi][nj] = __builtin_amdgcn_mfma_f32_16x16x32_bf16(A1h[mi], Bh, accB[mi][nj], 0, 0, 0);
                accB[mi][nj] = __builtin_amdgcn_mfma_f32_16x16x32_bf16(A1h[mi], Bl, accB[mi][nj], 0, 0, 0);
                accB[mi][nj] = __builtin_amdgcn_mfma_f32_16x16x32_bf16(A1l[mi], Bh, accB[mi][nj], 0, 0, 0);
            }
        }
        __syncthreads();
    }
    r2c192_epilogue(accA, accB, col0, njN, y0, wave, lm, lq, twT, outp, B, plane);
}

// ---------------- radix-2 MFMA row pass R2C (pre-split de-interleaved H/L source) --------
__global__ __launch_bounds__(256) void r2c192_s(
    const u16* __restrict__ Hs, const u16* __restrict__ Ls,
    int inH, int inW, int offY, int offX,
    const u16* __restrict__ TH, const u16* __restrict__ TL,
    const float2* __restrict__ twT,
    uint2* __restrict__ outp, int B)
{
    __shared__ u16 AhS[2][8*64*8];
    __shared__ u16 AlS[2][8*64*8];
    int col0 = blockIdx.x * 64;
    int y0   = blockIdx.y * 128;
    int plane = blockIdx.z;
    int njN = (col0 >= 192) ? 1 : 4;
    int tid = threadIdx.x;
    int wave = tid >> 6, lane = tid & 63;
    int lm = lane & 15, lq = lane >> 4;
    f32x4 accA[2][4], accB[2][4];
#pragma unroll
    for (int mi = 0; mi < 2; ++mi)
#pragma unroll
        for (int nj = 0; nj < 4; ++nj) {
            accA[mi][nj] = (f32x4){0.f,0.f,0.f,0.f};
            accB[mi][nj] = (f32x4){0.f,0.f,0.f,0.f};
        }
    const u16* hP = Hs + (size_t)plane*inH*inW;
    const u16* lP = Ls + (size_t)plane*inH*inW;
    int W2  = inW >> 1;
    int ox2 = offX >> 1;
    bool al16 = ((ox2 & 7) == 0);
    int mhi = (offX + inW) >> 1;   // offX even
    for (int kt = 0; kt < mhi; kt += 32) {
        // slots: 2 parities x 128 rows x 4 kq2 (8 m each) = 1024
#pragma unroll
        for (int s = 0; s < 4; ++s) {
            int slot = tid + s*256;
            int p    = slot >> 9;
            int inr  = slot & 511;
            int r = inr >> 2, kq2 = inr & 3;
            int yy = y0 + r - offY;
            int m0 = kt + kq2*8;
            int pos = m0 - ox2;
            uint4 hq = {0u,0u,0u,0u}, lq4 = {0u,0u,0u,0u};
            if (yy >= 0 && yy < inH) {
                const u16* hr = hP + (size_t)yy*inW + (size_t)p*W2;
                const u16* lr = lP + (size_t)yy*inW + (size_t)p*W2;
                if (pos >= 0 && pos + 8 <= W2) {
                    if (al16) {
                        hq  = *(const uint4*)(hr + pos);
                        lq4 = *(const uint4*)(lr + pos);
                    } else {
                        hq.x = *(const u32*)(hr+pos);   hq.y = *(const u32*)(hr+pos+2);
                        hq.z = *(const u32*)(hr+pos+4); hq.w = *(const u32*)(hr+pos+6);
                        lq4.x = *(const u32*)(lr+pos);   lq4.y = *(const u32*)(lr+pos+2);
                        lq4.z = *(const u32*)(lr+pos+4); lq4.w = *(const u32*)(lr+pos+6);
                    }
                } else if (pos + 8 > 0 && pos < W2) {
#pragma unroll
                    for (int q = 0; q < 4; ++q) {
                        int pp = pos + 2*q;
                        if (pp >= 0 && pp + 2 <= W2) {
                            ((u32*)&hq)[q]  = *(const u32*)(hr+pp);
                            ((u32*)&lq4)[q] = *(const u32*)(lr+pp);
                        }
                    }
                }
            }
            int base = ((r >> 4)*64 + (r & 15) + 16*kq2)*8;
            *(uint4*)&AhS[p][base] = hq;
            *(uint4*)&AlS[p][base] = lq4;
        }
        __syncthreads();
        short8 A0h[2], A0l[2], A1h[2], A1l[2];
#pragma unroll
        for (int mi = 0; mi < 2; ++mi) {
            int fo = ((wave*2 + mi)*64 + lane)*8;
            A0h[mi] = *(const short8*)&AhS[0][fo];
            A0l[mi] = *(const short8*)&AlS[0][fo];
            A1h[mi] = *(const short8*)&AhS[1][fo];
            A1l[mi] = *(const short8*)&AlS[1][fo];
        }
#pragma unroll
        for (int nj = 0; nj < 4; ++nj) {
            if (nj >= njN) continue;
            size_t toff = (size_t)(col0 + nj*16 + lm)*192 + kt + lq*8;
            short8 Bh = *(const short8*)(TH + toff);
            short8 Bl = *(const short8*)(TL + toff);
#pragma unroll
            for (int mi = 0; mi < 2; ++mi) {
                accA[mi][nj] = __builtin_amdgcn_mfma_f32_16x16x32_bf16(A0h[mi], Bh, accA[mi][nj], 0, 0, 0);
                accA[mi][nj] = __builtin_amdgcn_mfma_f32_16x16x32_bf16(A0h[mi], Bl, accA[mi][nj], 0, 0, 0);
                accA[mi][nj] = __builtin_amdgcn_mfma_f32_16x16x32_bf16(A0l[mi], Bh, accA[mi][nj], 0, 0, 0);
                accB[mi][nj] = __builtin_amdgcn_mfma_f32_16x16x32_bf16(A1h[mi], Bh, accB[mi][nj], 0, 0, 0);
                accB[mi][nj] = __builtin_amdgcn_mfma_f32_16x16x32_bf16(A1h[mi], Bl, accB[mi][nj], 0, 0, 0);
                accB[mi][nj] = __builtin_amdgcn_mfma_f32_16x16x32_bf16(A1l[mi], Bh, accB[mi][nj], 0, 0, 0);
            }
        }
        __syncthreads();
    }
    r2c192_epilogue(accA, accB, col0, njN, y0, wave, lm, lq, twT, outp, B, plane);
}

// ---------------- lse combine ----------------
__device__ __forceinline__ void lse_comb(float& m, float& s, float m2, float s2)
{
    if (m2 > m) { s = s * expf(m - m2) + s2; m = m2; }
    else        { s = s + s2 * expf(m2 - m); }
}

// ---------------- pre-twiddle for radix-2 C2R: in-place G+/G- over spectrum rows ------
__global__ void gpm_kernel(uint2* __restrict__ S, const float2* __restrict__ twT, int rows)
{
    int idx = blockIdx.x*256 + threadIdx.x;
    if (idx >= rows * 97) return;
    int j = idx % 97;
    size_t b = (size_t)(idx / 97) * KF;
    if (j == 96) {
        float2 f = ldc(S, b + 96);
        S[b + 96] = packc(2.f*f.x, -2.f*f.y);
    } else {
        float2 f1 = ldc(S, b + j);
        float2 f2 = ldc(S, b + 192 - j);
        float gpx = f1.x + f2.x, gpy = f1.y - f2.y;
        float hx  = f1.x - f2.x, hy  = f1.y + f2.y;
        float2 tw = twT[j];
        float gmx = tw.x*hx - tw.y*hy;
        float gmy = tw.x*hy + tw.y*hx;
        S[b + j]       = packc(gpx, gpy);
        S[b + 192 - j] = packc(gmx, gmy);
    }
}

// ---------------- radix-2 MFMA row pass C2R (consumes pre-twiddled spectrum) ----------
// FUSE_LSE instantiation adds per-block LSE partials (used only for the kernel image).
template<bool FUSE_LSE>
__global__ __launch_bounds__(256) void c2r192(
    const uint2* __restrict__ Ain,
    const u16* __restrict__ UH, const u16* __restrict__ UL,
    float* __restrict__ outp, const float* __restrict__ thr,
    u16* __restrict__ spH, u16* __restrict__ spL, int B,
    float2* __restrict__ parts)
{
    __shared__ u16 AhS[2][8*64*8];
    __shared__ u16 AlS[2][8*64*8];
    int col0 = blockIdx.x * 64;      // m-tile
    int y0   = blockIdx.y * 128;
    int plane = blockIdx.z;
    int tid = threadIdx.x;
    int wave = tid >> 6, lane = tid & 63;
    int lm = lane & 15, lq = lane >> 4;
    f32x4 accP[2][4], accQ[2][4];
#pragma unroll
    for (int mi = 0; mi < 2; ++mi)
#pragma unroll
        for (int nj = 0; nj < 4; ++nj) {
            accP[mi][nj] = (f32x4){0.f,0.f,0.f,0.f};
            accQ[mi][nj] = (f32x4){0.f,0.f,0.f,0.f};
        }
    for (int kt = 0; kt < 194; kt += 32) {
#pragma unroll
        for (int s = 0; s < 8; ++s) {
            int slot = tid + s*256;
            int p   = slot >> 10;
            int inr = slot & 1023;
            int r = inr >> 3, kq = inr & 7;
            size_t rowb = ((size_t)(y0 + r)*B + plane)*KF;
            int j0 = (kt + kq*4) >> 1;   // always even
            uint2 u0, u1;
            u0.x = u0.y = u1.x = u1.y = 0u;
            if (p == 0) {
                if (j0 < 96) u0 = Ain[rowb + j0];
                else if (j0 == 96) {
                    uint2 t = Ain[rowb + 96];
                    u0.x = t.x & 0xffffu; u0.y = t.y & 0xffffu;
                }
                if (j0 + 1 < 96) u1 = Ain[rowb + j0 + 1];
            } else {
                if (j0 < 96) u0 = Ain[rowb + 192 - j0];
                else if (j0 == 96) {
                    uint2 t = Ain[rowb + 96];
                    u0.x = t.x >> 16; u0.y = t.y >> 16;
                }
                if (j0 + 1 < 96) u1 = Ain[rowb + 191 - j0];
            }
            int base = ((r >> 4)*64 + (r & 15) + 16*(kq >> 1))*8 + (kq & 1)*4;
            uint2 hp, lp;
            hp.x = u0.x; hp.y = u1.x;
            lp.x = u0.y; lp.y = u1.y;
            *(uint2*)&AhS[p][base] = hp;
            *(uint2*)&AlS[p][base] = lp;
        }
        __syncthreads();
        short8 A0h[2], A0l[2], A1h[2], A1l[2];
#pragma unroll
        for (int mi = 0; mi < 2; ++mi) {
            int fo = ((wave*2 + mi)*64 + lane)*8;
            A0h[mi] = *(const short8*)&AhS[0][fo];
            A0l[mi] = *(const short8*)&AlS[0][fo];
            A1h[mi] = *(const short8*)&AhS[1][fo];
            A1l[mi] = *(const short8*)&AlS[1][fo];
        }
#pragma unroll
        for (int nj = 0; nj < 4; ++nj) {
            size_t toff = (size_t)(col0 + nj*16 + lm)*224 + kt + lq*8;
            short8 Bh = *(const short8*)(UH + toff);
            short8 Bl = *(const short8*)(UL + toff);
#pragma unroll
            for (int mi = 0; mi < 2; ++mi) {
                accP[mi][nj] = __builtin_amdgcn_mfma_f32_16x16x32_bf16(A0h[mi], Bh, accP[mi][nj], 0, 0, 0);
                accP[mi][nj] = __builtin_amdgcn_mfma_f32_16x16x32_bf16(A0h[mi], Bl, accP[mi][nj], 0, 0, 0);
                accP[mi][nj] = __builtin_amdgcn_mfma_f32_16x16x32_bf16(A0l[mi], Bh, accP[mi][nj], 0, 0, 0);
                accQ[mi][nj] = __builtin_amdgcn_mfma_f32_16x16x32_bf16(A1h[mi], Bh, accQ[mi][nj], 0, 0, 0);
                accQ[mi][nj] = __builtin_amdgcn_mfma_f32_16x16x32_bf16(A1h[mi], Bl, accQ[mi][nj], 0, 0, 0);
                accQ[mi][nj] = __builtin_amdgcn_mfma_f32_16x16x32_bf16(A1l[mi], Bh, accQ[mi][nj], 0, 0, 0);
            }
        }
        __syncthreads();
    }
    float bthr = thr ? thr[plane & 15] : 0.f;
    float lm_ = -1e30f, ls_ = 0.f;
#pragma unroll
    for (int mi = 0; mi < 2; ++mi) {
#pragma unroll
        for (int nj = 0; nj < 4; ++nj) {
            int m = col0 + nj*16 + lm;
#pragma unroll
            for (int rr = 0; rr < 4; ++rr) {
                int y = y0 + wave*32 + mi*16 + lq*4 + rr;
                float xe = accP[mi][nj][rr];
                float xo = accQ[mi][nj][rr];
                float2 o2; o2.x = xe; o2.y = xo;
                *(float2*)&outp[((size_t)plane*FH + y)*FH + 2*m] = o2;
                if (spH) {
                    float s0 = softt(xe, bthr), s1 = softt(xo, bthr);
                    u16 h0 = bf16_rn(s0), h1 = bf16_rn(s1);
                    u16 l0 = bf16_rn(s0 - bf16_to_f(h0)), l1 = bf16_rn(s1 - bf16_to_f(h1));
                    size_t d = (size_t)plane*SPW + (size_t)y*FH + m;
                    spH[d]       = h0; spL[d]       = l0;
                    spH[d + 192] = h1; spL[d + 192] = l1;
                }
                if (FUSE_LSE) {
                    lse_comb(lm_, ls_, 100.f*xe, 1.f);
                    lse_comb(lm_, ls_, 100.f*xo, 1.f);
                }
            }
        }
    }
    if (FUSE_LSE) {
        __shared__ float sm[256], ss[256];
        sm[tid] = lm_; ss[tid] = ls_;
        __syncthreads();
        for (int st = 128; st > 0; st >>= 1) {
            if (tid < st) {
                float mm = sm[tid], sc = ss[tid];
                lse_comb(mm, sc, sm[tid+st], ss[tid+st]);
                sm[tid] = mm; ss[tid] = sc;
            }
            __syncthreads();
        }
        if (tid == 0) {
            float2 o; o.x = sm[0]; o.y = ss[0];
            parts[plane*9 + blockIdx.y*3 + blockIdx.x] = o;
        }
    }
}

// ---------------- MFMA col pass, radix-8 DIT (standalone) ----------------
// 384-pt DFT over rows n=8m+p: C_p = 48-pt DFT of x[8m+p] (shared E48, K=96 stacked).
// X[h0+48q] = sum_p (C_p(h0) * W^(p*h0)) * w8^(pq), fused 8-pt butterfly in fp32 epilogue.
// 384 threads (6 waves x 16 rows = all 96 stacked rows), 1D grid; N-tile 32.
__global__ __launch_bounds__(384) void zgemm_col_mfma8(
    const u16* __restrict__ EH, const u16* __restrict__ EL,
    const uint2* __restrict__ Bm, uint2* __restrict__ Cm, int N, float sgn,
    int ktHi, const float2* __restrict__ twT)
{
    __shared__ u16 BhS[8][2*64*8];
    __shared__ u16 BlS[8][2*64*8];
    int col0 = blockIdx.x * 32;
    int tid = threadIdx.x;
    int wave = tid >> 6, lane = tid & 63;
    int lm = lane & 15, lq = lane >> 4;
    f32x4 acc[8][2];
#pragma unroll
    for (int p = 0; p < 8; ++p)
#pragma unroll
        for (int nj = 0; nj < 2; ++nj)
            acc[p][nj] = (f32x4){0.f,0.f,0.f,0.f};
    int arow = wave*16 + lm;   // [0,96)
    for (int kt = 0; kt < ktHi; kt += 32) {
        int tbase = kt >> 1;
#pragma unroll
        for (int s = 0; s < 6; ++s) {
            int slot = tid + s*384;
            if (slot < 2048) {
                int p    = slot >> 8;
                int inr  = slot & 255;
                int pair = inr >> 5;
                int n    = inr & 31;
                int gn   = col0 + n;
                int t0   = tbase + pair*2;
                uint2 u0, u1;
                u0.x = u0.y = u1.x = u1.y = 0u;
                if (gn < N) {
                    u0 = Bm[(size_t)(8*t0 + p)*N + gn];
                    u1 = Bm[(size_t)(8*t0 + 8 + p)*N + gn];
                }
                int ntile = n >> 4, n0 = n & 15;
                int lrow  = (pair >> 1)*16 + n0;
                int base  = (ntile*64 + lrow)*8 + (pair & 1)*4;
                uint2 hp, lp;
                hp.x = u0.x; hp.y = u1.x;
                lp.x = u0.y; lp.y = u1.y;
                *(uint2*)&BhS[p][base] = hp;
                *(uint2*)&BlS[p][base] = lp;
            }
        }
        __syncthreads();
        short8 Ah, Al;
        {
            size_t aoff = (size_t)arow*96 + kt + lq*8;
            Ah = *(const short8*)(EH + aoff);
            Al = *(const short8*)(EL + aoff);
        }
#pragma unroll
        for (int nj = 0; nj < 2; ++nj) {
#pragma unroll
            for (int p = 0; p < 8; ++p) {
                short8 Bh = *(const short8*)&BhS[p][(nj*64 + lane)*8];
                short8 Bl = *(const short8*)&BlS[p][(nj*64 + lane)*8];
                acc[p][nj] = __builtin_amdgcn_mfma_f32_16x16x32_bf16(Ah, Bh, acc[p][nj], 0, 0, 0);
                acc[p][nj] = __builtin_amdgcn_mfma_f32_16x16x32_bf16(Ah, Bl, acc[p][nj], 0, 0, 0);
                acc[p][nj] = __builtin_amdgcn_mfma_f32_16x16x32_bf16(Al, Bh, acc[p][nj], 0, 0, 0);
            }
        }
        __syncthreads();
    }
#pragma unroll
    for (int nj = 0; nj < 2; ++nj) {
        int coln = col0 + nj*16 + lm;
        if (coln < N) {
            int r0 = wave*16 + lq*4;
            int h0b = r0 >> 1;
#pragma unroll
            for (int pp = 0; pp < 2; ++pp) {
                int h0 = h0b + pp;    // [0,48)
                float2 cc[8];
#pragma unroll
                for (int p = 0; p < 8; ++p) {
                    cc[p].x = acc[p][nj][2*pp]; cc[p].y = acc[p][nj][2*pp+1];
                }
                float2 X[8];
                bfly8(cc, h0, sgn, twT, X);
#pragma unroll
                for (int q = 0; q < 8; ++q) {
                    int row = h0 + 48*q;
                    Cm[(size_t)row*N + coln] = packc(X[q].x, X[q].y);
                }
            }
        }
    }
}

// ---------------- FUSED: forward col pass + fg update + inverse col pass ----------------
// Forward (EH/EL, sgn=-1) of Bm -> Ffy written; fg(Fz,Ffy,Fk) computed per output and
// parked in registers (bit-identical to the old FzFg store); inverse (IH/IL, sgn=+1)
// staged register->LDS (scatter by row->(p=row&7, t=row>>3)) and written back into Bm.
// Bm is read fully (barrier-drained) before its columns are overwritten; columns are
// block-disjoint, so in-place is safe.
__global__ __launch_bounds__(384) void zgemm_fg_inv(
    const u16* __restrict__ EH, const u16* __restrict__ EL,
    const u16* __restrict__ IH, const u16* __restrict__ IL,
    uint2* __restrict__ Bm, uint2* __restrict__ Ffy,
    const uint2* __restrict__ FzB, const uint2* __restrict__ FkB,
    const float* __restrict__ zet16, int N, int GKF,
    const float2* __restrict__ twT)
{
    __shared__ u16 BhS[8][2*64*8];
    __shared__ u16 BlS[8][2*64*8];
    int col0 = blockIdx.x * 32;
    int tid = threadIdx.x;
    int wave = tid >> 6, lane = tid & 63;
    int lm = lane & 15, lq = lane >> 4;
    int arow = wave*16 + lm;   // [0,96)
    // ---------------- forward ----------------
    f32x4 acc[8][2];
#pragma unroll
    for (int p = 0; p < 8; ++p)
#pragma unroll
        for (int nj = 0; nj < 2; ++nj)
            acc[p][nj] = (f32x4){0.f,0.f,0.f,0.f};
    for (int kt = 0; kt < 96; kt += 32) {
        int tbase = kt >> 1;
#pragma unroll
        for (int s = 0; s < 6; ++s) {
            int slot = tid + s*384;
            if (slot < 2048) {
                int p    = slot >> 8;
                int inr  = slot & 255;
                int pair = inr >> 5;
                int n    = inr & 31;
                int gn   = col0 + n;
                int t0   = tbase + pair*2;
                uint2 u0, u1;
                u0.x = u0.y = u1.x = u1.y = 0u;
                if (gn < N) {
                    u0 = Bm[(size_t)(8*t0 + p)*N + gn];
                    u1 = Bm[(size_t)(8*t0 + 8 + p)*N + gn];
                }
                int ntile = n >> 4, n0 = n & 15;
                int lrow  = (pair >> 1)*16 + n0;
                int base  = (ntile*64 + lrow)*8 + (pair & 1)*4;
                uint2 hp, lp;
                hp.x = u0.x; hp.y = u1.x;
                lp.x = u0.y; lp.y = u1.y;
                *(uint2*)&BhS[p][base] = hp;
                *(uint2*)&BlS[p][base] = lp;
            }
        }
        __syncthreads();
        short8 Ah, Al;
        {
            size_t aoff = (size_t)arow*96 + kt + lq*8;
            Ah = *(const short8*)(EH + aoff);
            Al = *(const short8*)(EL + aoff);
        }
#pragma unroll
        for (int nj = 0; nj < 2; ++nj) {
#pragma unroll
            for (int p = 0; p < 8; ++p) {
                short8 Bh = *(const short8*)&BhS[p][(nj*64 + lane)*8];
                short8 Bl = *(const short8*)&BlS[p][(nj*64 + lane)*8];
                acc[p][nj] = __builtin_amdgcn_mfma_f32_16x16x32_bf16(Ah, Bh, acc[p][nj], 0, 0, 0);
                acc[p][nj] = __builtin_amdgcn_mfma_f32_16x16x32_bf16(Ah, Bl, acc[p][nj], 0, 0, 0);
                acc[p][nj] = __builtin_amdgcn_mfma_f32_16x16x32_bf16(Al, Bh, acc[p][nj], 0, 0, 0);
            }
        }
        __syncthreads();
    }
    // ---------------- fwd epilogue: butterfly + Ffy write + fg -> parked pg ----------------
    int r0 = wave*16 + lq*4;
    int h0b = r0 >> 1;
    uint2 pg[2][2][8];
#pragma unroll
    for (int nj = 0; nj < 2; ++nj)
#pragma unroll
        for (int pp = 0; pp < 2; ++pp)
#pragma unroll
            for (int q = 0; q < 8; ++q) { pg[nj][pp][q].x = 0u; pg[nj][pp][q].y = 0u; }
#pragma unroll
    for (int nj = 0; nj < 2; ++nj) {
        int coln = col0 + nj*16 + lm;
        if (coln < N) {
            int planeI = coln / KF;
            int kk = coln - planeI*KF;
            int imgI = planeI >> 4;
            float zeta = 10.f * zet16[planeI & 15];
#pragma unroll
            for (int pp = 0; pp < 2; ++pp) {
                int h0 = h0b + pp;    // [0,48)
                float2 cc[8];
#pragma unroll
                for (int p = 0; p < 8; ++p) {
                    cc[p].x = acc[p][nj][2*pp]; cc[p].y = acc[p][nj][2*pp+1];
                }
                float2 X[8];
                bfly8(cc, h0, -1.f, twT, X);
#pragma unroll
                for (int q = 0; q < 8; ++q) {
                    int row = h0 + 48*q;
                    uint2 px = packc(X[q].x, X[q].y);
                    Ffy[(size_t)row*N + coln] = px;
                    float2 fy = ldcu(px);
                    float2 fz = ldc(FzB, (size_t)row*N + coln);
                    float2 fk = ldc(FkB, (size_t)row*GKF + imgI*KF + kk);
                    float nx = zeta*(fk.x*fy.x + fk.y*fy.y) + fz.x;
                    float ny = zeta*(fk.x*fy.y - fk.y*fy.x) + fz.y;
                    float den = zeta*(fk.x*fk.x + fk.y*fk.y) + 1.f + 1e-8f;
                    float inv = 1.f/den;
                    pg[nj][pp][q] = packc(nx*inv, ny*inv);
                }
            }
        }
    }
    // ---------------- inverse: 3 LDS-staged K-steps ----------------
    f32x4 iacc[8][2];
#pragma unroll
    for (int p = 0; p < 8; ++p)
#pragma unroll
        for (int nj = 0; nj < 2; ++nj)
            iacc[p][nj] = (f32x4){0.f,0.f,0.f,0.f};
    for (int s = 0; s < 3; ++s) {
        __syncthreads();   // previous step's LDS reads (or fwd) complete before overwrite
        // scatter parked pg into the staging layout: row -> (p=row&7, t=row>>3)
#pragma unroll
        for (int nj = 0; nj < 2; ++nj) {
#pragma unroll
            for (int pp = 0; pp < 2; ++pp) {
                int h0 = h0b + pp;
                int dd = h0 >> 3;
                int p  = h0 & 7;       // (h0+48q)&7 == h0&7
#pragma unroll
                for (int q = 0; q < 8; ++q) {
                    int t = 6*q + dd;  // (h0+48q)>>3
                    if ((t >> 4) == s) {
                        int pair = (t >> 1) & 7;
                        int off  = t & 1;
                        int idx  = (nj*64 + (pair>>1)*16 + lm)*4 + (pair&1)*2 + off;
                        ((u32*)BhS[p])[idx] = pg[nj][pp][q].x;
                        ((u32*)BlS[p])[idx] = pg[nj][pp][q].y;
                    }
                }
            }
        }
        __syncthreads();
        short8 Ah, Al;
        {
            size_t aoff = (size_t)arow*96 + 32*s + lq*8;
            Ah = *(const short8*)(IH + aoff);
            Al = *(const short8*)(IL + aoff);
        }
#pragma unroll
        for (int nj = 0; nj < 2; ++nj) {
#pragma unroll
            for (int p = 0; p < 8; ++p) {
                short8 Bh = *(const short8*)&BhS[p][(nj*64 + lane)*8];
                short8 Bl = *(const short8*)&BlS[p][(nj*64 + lane)*8];
                iacc[p][nj] = __builtin_amdgcn_mfma_f32_16x16x32_bf16(Ah, Bh, iacc[p][nj], 0, 0, 0);
                iacc[p][nj] = __builtin_amdgcn_mfma_f32_16x16x32_bf16(Ah, Bl, iacc[p][nj], 0, 0, 0);
                iacc[p][nj] = __builtin_amdgcn_mfma_f32_16x16x32_bf16(Al, Bh, iacc[p][nj], 0, 0, 0);
            }
        }
    }
    // ---------------- inverse epilogue: butterfly (sgn=+1) -> Bm (in place) ----------------
#pragma unroll
    for (int nj = 0; nj < 2; ++nj) {
        int coln = col0 + nj*16 + lm;
        if (coln < N) {
#pragma unroll
            for (int pp = 0; pp < 2; ++pp) {
                int h0 = h0b + pp;
                float2 cc[8];
#pragma unroll
                for (int p = 0; p < 8; ++p) {
                    cc[p].x = iacc[p][nj][2*pp]; cc[p].y = iacc[p][nj][2*pp+1];
                }
                float2 X[8];
                bfly8(cc, h0, 1.f, twT, X);
#pragma unroll
                for (int q = 0; q < 8; ++q) {
                    int row = h0 + 48*q;
                    Bm[(size_t)row*N + coln] = packc(X[q].x, X[q].y);
                }
            }
        }
    }
}

// ---------------- elementwise frequency-domain updates (uint2 spectra) ----------------
__global__ void knum_kernel(const uint2* __restrict__ Fz, const uint2* __restrict__ Ffy,
                            const uint2* __restrict__ Fk, const float* __restrict__ kprox,
                            int L, int total, uint2* __restrict__ outk)
{
    int idx = blockIdx.x*256 + threadIdx.x;
    if (idx >= total) return;
    int k = idx % KF; int r = idx / KF;
    float zk = kprox[L];
    float s1x = 0.f, s1y = 0.f, s2 = 0.f;
    for (int c = 0; c < 16; ++c) {
        size_t bi = ((size_t)r*16 + c)*KF + k;
        float2 fz = ldc(Fz, bi), fy = ldc(Ffy, bi);
        s1x += fz.x*fy.x + fz.y*fy.y;
        s1y += fz.x*fy.y - fz.y*fy.x;
        s2  += fz.x*fz.x + fz.y*fz.y;
    }
    float2 fk = ldc(Fk, idx);
    float nx = zk*s1x + fk.x, ny = zk*s1y + fk.y;
    float den = zk*s2 + 1.f + 1e-8f;
    float inv = 1.f/den;
    outk[idx] = packc(nx*inv, ny*inv);
}

__global__ void zero_kernel(float* __restrict__ p, int n)
{
    int i = blockIdx.x*256 + threadIdx.x;
    if (i < n) p[i] = 0.f;
}

__global__ void kdelta_kernel(float* __restrict__ kful, int G)
{
    int t = threadIdx.x;
    if (t < G) kful[(size_t)t*FH*FH + 22*FH + 22] = 1.f;
}

// merged: final LSE reduce over 9 block-partials + threshold/normalize/write
__global__ __launch_bounds__(256) void knew_kernel(const float2* __restrict__ parts,
    const float* __restrict__ kraw0, const float* __restrict__ kb, int L,
    float* __restrict__ kful0)
{
    int img = blockIdx.x;
    const float* kraw = kraw0 + (size_t)img*FH*FH;
    float*       kful = kful0 + (size_t)img*FH*FH;
    int t = threadIdx.x;
    __shared__ float sm[16], ss[16];
    if (t < 16) {
        if (t < 9) { float2 p = parts[img*9 + t]; sm[t] = p.x; ss[t] = p.y; }
        else       { sm[t] = -1e30f; ss[t] = 0.f; }
    }
    __syncthreads();
    for (int st = 8; st > 0; st >>= 1) {
        if (t < st) {
            float mm = sm[t], sc = ss[t];
            lse_comb(mm, sc, sm[t+st], ss[t+st]);
            sm[t] = mm; ss[t] = sc;
        }
        __syncthreads();
    }
    float kmax = (sm[0] + logf(ss[0])) * 0.01f;
    float thr = 0.01f * kb[L] * kmax;
    float vs[8]; float loc = 0.f;
#pragma unroll
    for (int ii = 0; ii < 8; ++ii) {
        int i = t + ii*256;
        float v = 0.f;
        if (i < 45*45) {
            int y = i/45, x = i - y*45;
            v = fmaxf(kraw[y*FH + x] - thr, 0.f);
        }
        vs[ii] = v; loc += v;
    }
    __shared__ float sr[256];
    sr[t] = loc; __syncthreads();
    for (int st = 128; st > 0; st >>= 1) { if (t < st) sr[t] += sr[t+st]; __syncthreads(); }
    float den = sr[0] + 1e-8f;
#pragma unroll
    for (int ii = 0; ii < 8; ++ii) {
        int i = t + ii*256;
        if (i < 45*45) {
            int y = i/45, x = i - y*45;
            float v = vs[ii] + ((y == 22 && x == 22) ? 1e-8f : 0.f);
            kful[y*FH + x] = v / den;
        }
    }
}

// ---------------- Fw0 (direct 9-term DFT of shifted 3x3), image-independent ----------------
__global__ void fw0_kernel(const float* __restrict__ w0c, const float2* __restrict__ Ef,
                           float2* __restrict__ Fw0)
{
    int idx = blockIdx.x*256 + threadIdx.x;
    if (idx >= 48*FH*KF) return;
    int k = idx % KF; int r = idx / KF;
    int c = r & 15; int r2 = r >> 4;
    int ci = r2 % 3; int h = r2 / 3;
    float accx = 0.f, accy = 0.f;
#pragma unroll
    for (int ky = 0; ky < 3; ++ky) {
        int a1 = ky - 1; if (a1 < 0) a1 += FH;
        float2 e1 = Ef[h*FH + a1];
#pragma unroll
        for (int kx = 0; kx < 3; ++kx) {
            int a2 = kx - 1; if (a2 < 0) a2 += FH;
            float2 e2 = Ef[k*FH + a2];
            float wv = w0c[((c*3 + ci)*3 + ky)*3 + kx];
            float tr = e1.x*e2.x - e1.y*e2.y;
            float ti = e1.x*e2.y + e1.y*e2.x;
            accx += wv*tr; accy += wv*ti;
        }
    }
    float2 o; o.x = accx; o.y = accy;
    Fw0[idx] = o;
}

// ---------------- final per-bin 3x3 Hermitian Wiener solve (uint2 spectra) ----------------
__global__ void wiener_kernel(const uint2* __restrict__ Fk, const uint2* __restrict__ Fy,
    const float2* __restrict__ Fw0, const uint2* __restrict__ Fg2,
    const float* __restrict__ eta, int G, int total, uint2* __restrict__ Fx)
{
    int idx = blockIdx.x*256 + threadIdx.x;
    if (idx >= total) return;
    int k = idx % KF; int r = idx / KF;
    int h = r / G;
    float2 fk = ldc(Fk, idx);
    float fksq = fk.x*fk.x + fk.y*fk.y;
    float2 fyr = ldc(Fy, ((size_t)3*r + 0)*KF + k);
    float2 fyg = ldc(Fy, ((size_t)3*r + 1)*KF + k);
    float2 fyb = ldc(Fy, ((size_t)3*r + 2)*KF + k);
    float Crr = fksq, Cgg = fksq, Cbb = fksq;
    float2 Crg, Crb, Cgb;
    Crg.x = Crg.y = Crb.x = Crb.y = Cgb.x = Cgb.y = 0.f;
    float2 Br, Bg, Bb;
    Br.x = fk.x*fyr.x + fk.y*fyr.y; Br.y = fk.x*fyr.y - fk.y*fyr.x;
    Bg.x = fk.x*fyg.x + fk.y*fyg.y; Bg.y = fk.x*fyg.y - fk.y*fyg.x;
    Bb.x = fk.x*fyb.x + fk.y*fyb.y; Bb.y = fk.x*fyb.y - fk.y*fyb.x;
    for (int c = 0; c < 16; ++c) {
        float es = 10.f * eta[c];
        float2 wr = Fw0[((size_t)h*48 +  0 + c)*KF + k];
        float2 wg = Fw0[((size_t)h*48 + 16 + c)*KF + k];
        float2 wb = Fw0[((size_t)h*48 + 32 + c)*KF + k];
        float2 g  = ldc(Fg2, ((size_t)r*16 + c)*KF + k);
        Crr += es*(wr.x*wr.x + wr.y*wr.y);
        Cgg += es*(wg.x*wg.x + wg.y*wg.y);
        Cbb += es*(wb.x*wb.x + wb.y*wb.y);
        Crg.x += es*(wr.x*wg.x + wr.y*wg.y); Crg.y += es*(wr.x*wg.y - wr.y*wg.x);
        Crb.x += es*(wr.x*wb.x + wr.y*wb.y); Crb.y += es*(wr.x*wb.y - wr.y*wb.x);
        Cgb.x += es*(wg.x*wb.x + wg.y*wb.y); Cgb.y += es*(wg.x*wb.y - wg.y*wb.x);
        Br.x += es*(wr.x*g.x + wr.y*g.y); Br.y += es*(wr.x*g.y - wr.y*g.x);
        Bg.x += es*(wg.x*g.x + wg.y*g.y); Bg.y += es*(wg.x*g.y - wg.y*g.x);
        Bb.x += es*(wb.x*g.x + wb.y*g.y); Bb.y += es*(wb.x*g.y - wb.y*g.x);
    }
    float Crg_sq = Crg.x*Crg.x + Crg.y*Crg.y;
    float Crb_sq = Crb.x*Crb.x + Crb.y*Crb.y;
    float Cgb_sq = Cgb.x*Cgb.x + Cgb.y*Cgb.y;
    float Irr = Cgg*Cbb - Cgb_sq;
    float Igg = Crr*Cbb - Crb_sq;
    float Ibb = Crr*Cgg - Crg_sq;
    float2 Irg, Irb, Igb;
    Irg.x = (Cgb.x*Crb.x + Cgb.y*Crb.y) - Cbb*Crg.x;
    Irg.y = (Cgb.x*Crb.y - Cgb.y*Crb.x) - Cbb*Crg.y;
    Irb.x = (Crg.x*Cgb.x - Crg.y*Cgb.y) - Cgg*Crb.x;
    Irb.y = (Crg.x*Cgb.y + Crg.y*Cgb.x) - Cgg*Crb.y;
    Igb.x = (Crg.x*Crb.x + Crg.y*Crb.y) - Crr*Cgb.x;
    Igb.y = (Crg.x*Crb.y - Crg.y*Crb.x) - Crr*Cgb.y;
    float tx_ = Crg.x*Cgb.x - Crg.y*Cgb.y;
    float ty_ = Crg.x*Cgb.y + Crg.y*Cgb.x;
    float den = Crr*Irr - Cgg*Crb_sq - Cbb*Crg_sq + 2.f*(tx_*Crb.x + ty_*Crb.y) + 1e-8f;
    float inv = 1.f/den;
    float ox, oy;
    ox = (Irr*Br.x + (Irg.x*Bg.x - Irg.y*Bg.y) + (Irb.x*Bb.x - Irb.y*Bb.y))*inv;
    oy = (Irr*Br.y + (Irg.x*Bg.y + Irg.y*Bg.x) + (Irb.x*Bb.y + Irb.y*Bb.x))*inv;
    Fx[((size_t)3*r + 0)*KF + k] = packc(ox, oy);
    ox = ((Irg.x*Br.x + Irg.y*Br.y) + Igg*Bg.x + (Igb.x*Bb.x - Igb.y*Bb.y))*inv;
    oy = ((Irg.x*Br.y - Irg.y*Br.x) + Igg*Bg.y + (Igb.x*Bb.y + Igb.y*Bb.x))*inv;
    Fx[((size_t)3*r + 1)*KF + k] = packc(ox, oy);
    ox = ((Irb.x*Br.x + Irb.y*Br.y) + (Igb.x*Bg.x + Igb.y*Bg.y) + Ibb*Bb.x)*inv;
    oy = ((Irb.x*Br.y - Irb.y*Br.x) + (Igb.x*Bg.y - Igb.y*Bg.x) + Ibb*Bb.y)*inv;
    Fx[((size_t)3*r + 2)*KF + k] = packc(ox, oy);
}

// ---------------- output assembly ----------------
__global__ void crop_kernel(const float* __restrict__ sp, float* __restrict__ outp, int total)
{
    int idx = blockIdx.x*256 + threadIdx.x;
    if (idx >= total) return;
    int x = idx & 255; int r = idx >> 8; int y = r & 255; int plane = r >> 8;
    outp[idx] = sp[((size_t)plane*FH + (y+22))*FH + (x+22)];
}

__global__ void kcopy_kernel(const float* __restrict__ kful, float* __restrict__ outp, int total)
{
    int idx = blockIdx.x*256 + threadIdx.x;
    if (idx >= total) return;
    int rem = idx % 2025; int img = idx / 2025;
    int x = rem % 45; int y = rem / 45;
    outp[idx] = kful[(size_t)img*FH*FH + y*FH + x];
}

// =====================================================================
extern "C" void kernel_launch(void* const* d_in, const int* in_sizes, int n_in,
                              void* d_out, int out_size, void* d_ws, size_t ws_size,
                              hipStream_t stream)
{
    (void)in_sizes; (void)n_in; (void)out_size;
    const float* blurred = (const float*)d_in[0];
    const float* w0      = (const float*)d_in[1];
    const float* wsw     = (const float*)d_in[2];
    const float* biases  = (const float*)d_in[3];
    const float* kbias   = (const float*)d_in[4];
    const float* kprox   = (const float*)d_in[5];
    const float* zetas   = (const float*)d_in[6];
    const float* eta     = (const float*)d_in[7];
    float* outp = (float*)d_out;

    auto al = [](size_t b) { return (b + 255) & ~(size_t)255; };
    auto need = [&](int G) -> size_t {
        size_t s = 0;
        s += al((size_t)FH*FH*8);                 // Ef
        s += al(384*8);                           // twT
        s += 4*al((size_t)96*96*2);               // E48 fwd/inv H/L
        s += 2*al((size_t)208*192*2);             // T192
        s += 2*al((size_t)192*224*2);             // U192
        s += al(432*4);                           // w0c
        s += 2*al((size_t)10*G*16*65536*2);       // fyH, fyL (split checkpoints)
        s += al((size_t)G*16*FH*FH*4);            // zsp fp32
        s += 2*al((size_t)G*16*SPW*2);            // zspSH, zspSL
        s += 3*al((size_t)G*16*FH*KF*8);          // mid, FzFg, Ffy (uint2)
        s += 4*al((size_t)G*FH*KF*8);             // Fk, kfA, kfB, kmid
        s += 2*al((size_t)G*FH*FH*4);             // kraw, kful
        s += 2*al((size_t)G*3*FH*KF*8);           // FyB, FxB
        s += al((size_t)G*64*8);                  // lseP
        return s;
    };
    int G = 4;
    while (G > 1 && need(G) > ws_size) G >>= 1;

    char* base = (char*)d_ws;
    size_t off = 0;
    auto alloc = [&](size_t bytes) -> void* {
        void* p = (void*)(base + off);
        off += (bytes + 255) & ~(size_t)255;
        return p;
    };
    float2* Ef   = (float2*)alloc((size_t)FH*FH*8);
    float2* twT  = (float2*)alloc(384*8);
    u16* EfH = (u16*)alloc((size_t)96*96*2);
    u16* EfL = (u16*)alloc((size_t)96*96*2);
    u16* EiH = (u16*)alloc((size_t)96*96*2);
    u16* EiL = (u16*)alloc((size_t)96*96*2);
    u16* T1H = (u16*)alloc((size_t)208*192*2);
    u16* T1L = (u16*)alloc((size_t)208*192*2);
    u16* U1H = (u16*)alloc((size_t)192*224*2);
    u16* U1L = (u16*)alloc((size_t)192*224*2);
    float*  w0cB = (float*)alloc(432*4);
    u16*    fyH  = (u16*)alloc((size_t)10*G*16*65536*2);
    u16*    fyL  = (u16*)alloc((size_t)10*G*16*65536*2);
    float*  zsp  = (float*)alloc((size_t)G*16*FH*FH*4);
    u16*    zspSH= (u16*)alloc((size_t)G*16*SPW*2);
    u16*    zspSL= (u16*)alloc((size_t)G*16*SPW*2);
    uint2*  mid  = (uint2*)alloc((size_t)G*16*FH*KF*8);
    uint2*  FzFg = (uint2*)alloc((size_t)G*16*FH*KF*8);
    uint2*  Ffy  = (uint2*)alloc((size_t)G*16*FH*KF*8);
    uint2*  Fk   = (uint2*)alloc((size_t)G*FH*KF*8);
    uint2*  kfA  = (uint2*)alloc((size_t)G*FH*KF*8);
    uint2*  kfB  = (uint2*)alloc((size_t)G*FH*KF*8);
    uint2*  kmid = (uint2*)alloc((size_t)G*FH*KF*8);
    float*  kraw = (float*)alloc((size_t)G*FH*FH*4);
    float*  kful = (float*)alloc((size_t)G*FH*FH*4);
    uint2*  FyB  = (uint2*)alloc((size_t)G*3*FH*KF*8);
    uint2*  FxB  = (uint2*)alloc((size_t)G*3*FH*KF*8);
    float2* lseP = (float2*)alloc((size_t)G*64*8);
    // Fw0 (28.45 MB) overlays fyH — dead by final stage
    float2* Fw0B = (float2*)fyH;

    // tables + weight prep (image-independent)
    init_ef_k<<<(FH*FH+255)/256, 256, 0, stream>>>(Ef);
    init_tw<<<2, 256, 0, stream>>>(twT);
    init_e48<<<(96*96+255)/256, 256, 0, stream>>>(EfH, EfL, 0);
    init_e48<<<(96*96+255)/256, 256, 0, stream>>>(EiH, EiL, 1);
    init_t192<<<(208*192+255)/256, 256, 0, stream>>>(T1H, T1L);
    init_u192<<<(192*224+255)/256, 256, 0, stream>>>(U1H, U1L);
    w0c_kernel<<<1, 64, 0, stream>>>(w0, w0cB);

    auto zgf = [&](const uint2* Bm, uint2* Cm, int Ncols) {
        zgemm_col_mfma8<<<dim3((Ncols+31)/32), 384, 0, stream>>>(
            EfH, EfL, Bm, Cm, Ncols, -1.f, 96, twT);
    };
    auto zgi = [&](const uint2* Bm, uint2* Cm, int Ncols) {
        zgemm_col_mfma8<<<dim3((Ncols+31)/32), 384, 0, stream>>>(
            EiH, EiL, Bm, Cm, Ncols, 1.f, 96, twT);
    };
    auto r2c = [&](const float* inp, int inH, int inW, int oY, int oX,
                   const float* thr, uint2* o, int B) {
        r2c192_f<<<dim3(4, 3, B), 256, 0, stream>>>(
            inp, inH, inW, inW, (size_t)inH*inW, oY, oX, thr, T1H, T1L, twT, o, B);
    };
    auto r2cs = [&](const u16* Hs, const u16* Ls, int inH, int inW, int oY, int oX,
                    uint2* o, int B) {
        r2c192_s<<<dim3(4, 3, B), 256, 0, stream>>>(
            Hs, Ls, inH, inW, oY, oX, T1H, T1L, twT, o, B);
    };
    auto c2r = [&](uint2* Ain, float* o, int B,
                   const float* thr, u16* sH, u16* sL) {
        int rows = FH * B;
        gpm_kernel<<<(rows*97 + 255)/256, 256, 0, stream>>>(Ain, twT, rows);
        c2r192<false><<<dim3(3, 3, B), 256, 0, stream>>>(
            Ain, U1H, U1L, o, thr, sH, sL, B, nullptr);
    };
    auto c2rk = [&](uint2* Ain, float* o, int B, float2* parts) {
        int rows = FH * B;
        gpm_kernel<<<(rows*97 + 255)/256, 256, 0, stream>>>(Ain, twT, rows);
        c2r192<true><<<dim3(3, 3, B), 256, 0, stream>>>(
            Ain, U1H, U1L, o, nullptr, nullptr, nullptr, B, parts);
    };
    // sparse kernel-image forward FFT into kmid (45x45 support).
    // Row pass writes spectra rows 0..127 (rows >=45 exact zeros).
    // Radix-8 col pass with ktHi=32 consumes data rows 8t+p <= 127 (one K-step).
    auto r2ck = [&]() {
        r2c192_f<<<dim3(4, 1, G), 256, 0, stream>>>(
            kful, 45, 45, FH, (size_t)FH*FH, 0, 0, nullptr, T1H, T1L, twT, kmid, G);
        zgemm_col_mfma8<<<dim3((G*KF+31)/32), 384, 0, stream>>>(
            EfH, EfL, kmid, Fk, G*KF, -1.f, 32, twT);
    };

    const size_t CKL = (size_t)G*16*65536;   // one split ck layer (u16 elements)

    for (int g0 = 0; g0 < 4; g0 += G) {
        const float* img = blurred + (size_t)g0*3*65536;

        // forward conv chain: split checkpoints (parity de-interleaved)
        conv3x3_kernel<<<dim3(16,16,G), 256, 0, stream>>>(
            img, nullptr, nullptr, w0cB, fyH, fyL, 3, 1, (size_t)3*65536);
        for (int l = 1; l < 10; ++l)
            conv3x3_kernel<<<dim3(16,16,G), 256, 0, stream>>>(
                nullptr, fyH + (size_t)(l-1)*CKL, fyL + (size_t)(l-1)*CKL,
                wsw + (size_t)(l-1)*2304,
                fyH + (size_t)l*CKL, fyL + (size_t)l*CKL, 16, 0, (size_t)16*65536);

        // z init (circshift + threshold b0) -> split, Fz
        int totZ = G*16*FH*FH;
        zinit_kernel<<<(totZ+255)/256, 256, 0, stream>>>(
            fyH + 9*CKL, fyL + 9*CKL, biases, zspSH, zspSL, totZ);
        r2cs(zspSH, zspSL, FH, FH, 0, 0, mid, G*16);
        zgf(mid, FzFg, G*16*KF);

        // k init = delta
        zero_kernel<<<(G*FH*FH+255)/256, 256, 0, stream>>>(kful, G*FH*FH);
        kdelta_kernel<<<1, 64, 0, stream>>>(kful, G);

        int totK = G*FH*KF;
        int NS = G*16*KF;
        for (int it = 0; it < 10; ++it) {
            int Lfy = 9 - it;
            r2ck();   // Fk first (needed by fused fg epilogue below)
            r2cs(fyH + (size_t)Lfy*CKL, fyL + (size_t)Lfy*CKL, 256, 256, 44, 44, mid, G*16);
            // FUSED: forward col pass -> Ffy, fg(Fz_old, Ffy, Fk), inverse col of Fg -> mid
            zgemm_fg_inv<<<dim3((NS+31)/32), 384, 0, stream>>>(
                EfH, EfL, EiH, EiL, mid, Ffy, FzFg, Fk, zetas + it*16, NS, G*KF, twT);
            // zsp = irfft(Fg) PRE-threshold; side-output = softt-split for next r2c
            c2r(mid, zsp, G*16, biases + (it+1)*16, zspSH, zspSL);
            r2cs(zspSH, zspSL, FH, FH, 0, 0, mid, G*16);   // pre-split, no conversions
            zgf(mid, FzFg, NS);                            // Fz_new
            knum_kernel<<<(totK+255)/256, 256, 0, stream>>>(FzFg, Ffy, Fk, kprox, it, totK, kfA);
            zgi(kfA, kfB, G*KF);
            c2rk(kfB, kraw, G, lseP);                      // + fused LSE partials
            knew_kernel<<<G, 256, 0, stream>>>(lseP, kraw, kbias, it, kful);
        }

        // ---- final stage (fyH/fyL dead; Fw0 overlay live) ----
        r2c(img, 256, 256, 44, 44, nullptr, mid, 3*G);
        zgf(mid, FyB, 3*G*KF);
        r2ck();
        // Fg2 = rfft(softt(zsp, b_final)) — from fp32 zsp with fused threshold
        r2c(zsp, FH, FH, 0, 0, biases + 11*16, mid, G*16);
        zgf(mid, FzFg, G*16*KF);
        fw0_kernel<<<(48*FH*KF+255)/256, 256, 0, stream>>>(w0cB, Ef, Fw0B);
        wiener_kernel<<<(totK+255)/256, 256, 0, stream>>>(Fk, FyB, Fw0B, FzFg, eta, G, totK, FxB);
        zgi(FxB, mid, 3*G*KF);
        c2r(mid, zsp, 3*G, nullptr, nullptr, nullptr);
        int totC = G*3*65536;
        crop_kernel<<<(totC+255)/256, 256, 0, stream>>>(zsp, outp + (size_t)g0*3*65536, totC);
        int totKC = G*2025;
        kcopy_kernel<<<(totKC+255)/256, 256, 0, stream>>>(kful, outp + 786432 + g0*2025, totKC);
    }
}